// Round 1
// baseline (1077.274 us; speedup 1.0000x reference)
//
#include <hip/hip_runtime.h>

// GCN 2-layer forward: x[N,256] -> GCNConv(W1,b1)+ReLU -> GCNConv(W2,b2) -> log_softmax
// Strategy: build CSR (by dst) on the fly each launch, pull-style aggregation,
// one wave per node. fp32 throughout (round 1: correctness-first).

#define BLK 256

__global__ void init_kernel(float* __restrict__ deg, int* __restrict__ counts, int n) {
    int i = blockIdx.x * blockDim.x + threadIdx.x;
    if (i < n) { deg[i] = 1.0f; counts[i] = 1; }  // self-loop: weight 1.0, one edge
}

__global__ void hist_kernel(const int* __restrict__ dst, const float* __restrict__ ew,
                            float* __restrict__ deg, int* __restrict__ counts, int E) {
    int e = blockIdx.x * blockDim.x + threadIdx.x;
    if (e < E) {
        int d = dst[e];
        atomicAdd(&deg[d], ew[e]);
        atomicAdd(&counts[d], 1);
    }
}

__global__ void dinv_kernel(float* __restrict__ deg, int n) {
    int i = blockIdx.x * blockDim.x + threadIdx.x;
    if (i < n) deg[i] = rsqrtf(deg[i]);  // deg >= 1 always (self-loop weight 1)
}

// Single-block exclusive scan of counts[0..n) -> row_ptr[0..n], cursor = row_ptr copy
__global__ void scan_kernel(const int* __restrict__ counts, int* __restrict__ row_ptr,
                            int* __restrict__ cursor, int n) {
    __shared__ int smem[1024];
    int tid = threadIdx.x;
    int chunk = (n + 1023) >> 10;
    int start = tid * chunk;
    int end = start + chunk; if (end > n) end = n; if (start > n) start = n;
    int sum = 0;
    for (int i = start; i < end; i++) sum += counts[i];
    smem[tid] = sum;
    __syncthreads();
    // Hillis-Steele inclusive scan over 1024 partials
    for (int off = 1; off < 1024; off <<= 1) {
        int add = (tid >= off) ? smem[tid - off] : 0;
        __syncthreads();
        smem[tid] += add;
        __syncthreads();
    }
    int run = smem[tid] - sum;  // exclusive prefix of this thread's chunk
    for (int i = start; i < end; i++) {
        row_ptr[i] = run;
        cursor[i] = run;
        run += counts[i];
    }
    if (tid == 1023) row_ptr[n] = smem[1023];
}

__global__ void fill_edges_kernel(const int* __restrict__ src, const int* __restrict__ dst,
                                  const float* __restrict__ ew, const float* __restrict__ dinv,
                                  int* __restrict__ cursor, int* __restrict__ col,
                                  float* __restrict__ val, int E) {
    int e = blockIdx.x * blockDim.x + threadIdx.x;
    if (e < E) {
        int s = src[e], d = dst[e];
        int pos = atomicAdd(&cursor[d], 1);
        col[pos] = s;
        val[pos] = dinv[s] * ew[e] * dinv[d];
    }
}

__global__ void fill_loops_kernel(const float* __restrict__ dinv, int* __restrict__ cursor,
                                  int* __restrict__ col, float* __restrict__ val, int n) {
    int i = blockIdx.x * blockDim.x + threadIdx.x;
    if (i < n) {
        int pos = atomicAdd(&cursor[i], 1);
        col[pos] = i;
        val[pos] = dinv[i] * dinv[i];  // self-loop weight 1.0
    }
}

// Tiled fp32 GEMM: C[M,N] = A[M,K] @ B[K,N]. BK=32, 4x4 register tile, 256 threads.
// Requires BM*BN == 4096, K % 32 == 0, N % 4 == 0.
template<int BM, int BN>
__global__ __launch_bounds__(256) void gemm_kernel(const float* __restrict__ A,
                                                   const float* __restrict__ B,
                                                   float* __restrict__ C,
                                                   int M, int K, int N) {
    __shared__ float As[32][BM];   // k-major (A transposed in LDS)
    __shared__ float Bs[32][BN];
    const int tid = threadIdx.x;
    const int block_row = blockIdx.x * BM;
    constexpr int COLG = BN / 4;
    const int tx = tid % COLG;     // col group -> cols tx*4..tx*4+3
    const int ty = tid / COLG;     // row group -> rows ty*4..ty*4+3

    float acc[4][4] = {};

    for (int k0 = 0; k0 < K; k0 += 32) {
        // Load A tile: BM rows x 32 k = BM*8 float4, one+ per thread
        #pragma unroll
        for (int i = tid; i < BM * 8; i += 256) {
            int r = i >> 3, kq = i & 7;
            int rr = block_row + r; if (rr > M - 1) rr = M - 1;
            float4 a = *(const float4*)(A + (size_t)rr * K + k0 + kq * 4);
            As[kq * 4 + 0][r] = a.x;
            As[kq * 4 + 1][r] = a.y;
            As[kq * 4 + 2][r] = a.z;
            As[kq * 4 + 3][r] = a.w;
        }
        // Load B tile: 32 x BN = 8*BN float4
        #pragma unroll
        for (int i = tid; i < 8 * BN; i += 256) {
            int kk = i / COLG, cq = i % COLG;
            *(float4*)(&Bs[kk][cq * 4]) = *(const float4*)(B + (size_t)(k0 + kk) * N + cq * 4);
        }
        __syncthreads();
        #pragma unroll
        for (int kk = 0; kk < 32; kk++) {
            float4 av = *(const float4*)(&As[kk][ty * 4]);
            float4 bv = *(const float4*)(&Bs[kk][tx * 4]);
            float a[4] = {av.x, av.y, av.z, av.w};
            float b[4] = {bv.x, bv.y, bv.z, bv.w};
            #pragma unroll
            for (int i = 0; i < 4; i++)
                #pragma unroll
                for (int j = 0; j < 4; j++)
                    acc[i][j] += a[i] * b[j];
        }
        __syncthreads();
    }
    #pragma unroll
    for (int i = 0; i < 4; i++) {
        int r = block_row + ty * 4 + i;
        if (r < M) {
            float4 o = make_float4(acc[i][0], acc[i][1], acc[i][2], acc[i][3]);
            *(float4*)(C + (size_t)r * N + tx * 4) = o;
        }
    }
}

// Layer-1 aggregation: one wave per node, 128 feats = float2 per lane. out = relu(agg + b1)
__global__ void agg1_kernel(const float* __restrict__ h, const int* __restrict__ row_ptr,
                            const int* __restrict__ col, const float* __restrict__ val,
                            const float* __restrict__ b1, float* __restrict__ out, int n) {
    int node = blockIdx.x * (blockDim.x >> 6) + (threadIdx.x >> 6);
    int lane = threadIdx.x & 63;
    if (node >= n) return;
    int beg = row_ptr[node], end = row_ptr[node + 1];
    float ax = 0.f, ay = 0.f;
    for (int e = beg; e < end; e++) {
        int s = col[e];
        float v = val[e];
        float2 hv = *(const float2*)(h + (size_t)s * 128 + lane * 2);
        ax += v * hv.x;
        ay += v * hv.y;
    }
    float2 bb = *(const float2*)(b1 + lane * 2);
    ax += bb.x; ay += bb.y;
    ax = ax > 0.f ? ax : 0.f;
    ay = ay > 0.f ? ay : 0.f;
    *(float2*)(out + (size_t)node * 128 + lane * 2) = make_float2(ax, ay);
}

// Layer-2 aggregation + bias + log_softmax: one wave per node, 64 feats = 1 per lane.
__global__ void agg2_kernel(const float* __restrict__ h2, const int* __restrict__ row_ptr,
                            const int* __restrict__ col, const float* __restrict__ val,
                            const float* __restrict__ b2, float* __restrict__ out, int n) {
    int node = blockIdx.x * (blockDim.x >> 6) + (threadIdx.x >> 6);
    int lane = threadIdx.x & 63;
    if (node >= n) return;
    int beg = row_ptr[node], end = row_ptr[node + 1];
    float acc = 0.f;
    for (int e = beg; e < end; e++) {
        acc += val[e] * h2[(size_t)col[e] * 64 + lane];
    }
    acc += b2[lane];
    // wave-wide max (64 lanes)
    float m = acc;
    #pragma unroll
    for (int off = 32; off > 0; off >>= 1) m = fmaxf(m, __shfl_xor(m, off));
    float ex = expf(acc - m);
    float s = ex;
    #pragma unroll
    for (int off = 32; off > 0; off >>= 1) s += __shfl_xor(s, off);
    out[(size_t)node * 64 + lane] = acc - m - logf(s);
}

extern "C" void kernel_launch(void* const* d_in, const int* in_sizes, int n_in,
                              void* d_out, int out_size, void* d_ws, size_t ws_size,
                              hipStream_t stream) {
    const float* x  = (const float*)d_in[0];
    const int*   ei = (const int*)d_in[1];
    const float* ew = (const float*)d_in[2];
    const float* W1 = (const float*)d_in[3];
    const float* b1 = (const float*)d_in[4];
    const float* W2 = (const float*)d_in[5];
    const float* b2 = (const float*)d_in[6];
    float* out = (float*)d_out;

    const int N = in_sizes[0] / 256;   // 100000
    const int E = in_sizes[1] / 2;     // 1600000
    const int Et = E + N;              // edges incl. self-loops
    const int* src = ei;
    const int* dst = ei + E;

    // Workspace carving (256B aligned)
    char* w = (char*)d_ws;
    size_t off = 0;
    auto carve = [&](size_t bytes) {
        void* p = w + off;
        off = (off + bytes + 255) & ~(size_t)255;
        return p;
    };
    float* deg     = (float*)carve((size_t)N * 4);        // becomes dinv in place
    int*   counts  = (int*)  carve((size_t)N * 4);
    int*   row_ptr = (int*)  carve((size_t)(N + 1) * 4);
    int*   cursor  = (int*)  carve((size_t)N * 4);
    int*   col     = (int*)  carve((size_t)Et * 4);
    float* val     = (float*)carve((size_t)Et * 4);
    float* bufA    = (float*)carve((size_t)N * 128 * 4);  // h = x@W1; later reused as h2
    float* bufB    = (float*)carve((size_t)N * 128 * 4);  // h1 = relu(agg+b1)
    float* bufC    = bufA;                                 // h2 = h1@W2 (aliases bufA, safe)

    const int gN = (N + BLK - 1) / BLK;
    const int gE = (E + BLK - 1) / BLK;

    // 1. CSR build
    init_kernel<<<gN, BLK, 0, stream>>>(deg, counts, N);
    hist_kernel<<<gE, BLK, 0, stream>>>(dst, ew, deg, counts, E);
    dinv_kernel<<<gN, BLK, 0, stream>>>(deg, N);
    scan_kernel<<<1, 1024, 0, stream>>>(counts, row_ptr, cursor, N);
    fill_edges_kernel<<<gE, BLK, 0, stream>>>(src, dst, ew, deg, cursor, col, val, E);
    fill_loops_kernel<<<gN, BLK, 0, stream>>>(deg, cursor, col, val, N);

    // 2. Layer 1: h = x @ W1  (100000x256 @ 256x128)
    gemm_kernel<32, 128><<<(N + 31) / 32, 256, 0, stream>>>(x, W1, bufA, N, 256, 128);
    //    h1 = relu(agg(h) + b1)
    agg1_kernel<<<(N + 3) / 4, 256, 0, stream>>>(bufA, row_ptr, col, val, b1, bufB, N);

    // 3. Layer 2: h2 = h1 @ W2  (100000x128 @ 128x64)
    gemm_kernel<64, 64><<<(N + 63) / 64, 256, 0, stream>>>(bufB, W2, bufC, N, 128, 64);
    //    out = log_softmax(agg(h2) + b2)
    agg2_kernel<<<(N + 3) / 4, 256, 0, stream>>>(bufC, row_ptr, col, val, b2, out, N);
}

// Round 2
// 872.422 us; speedup vs baseline: 1.2348x; 1.2348x over previous
//
#include <hip/hip_runtime.h>

// GCN 2-layer forward: x[N,256] -> GCNConv(W1,b1)+ReLU -> GCNConv(W2,b2) -> log_softmax
// Strategy: build CSR (by dst) on the fly each launch, pull-style aggregation,
// one wave per node. fp32 throughout.
// R1: multi-block scan (was 230us single-block -> target <10us).

#define BLK 256
#define SCAN_CHUNK 2048  // elements per scan block (256 threads x 8)

__global__ void init_kernel(float* __restrict__ deg, int* __restrict__ counts, int n) {
    int i = blockIdx.x * blockDim.x + threadIdx.x;
    if (i < n) { deg[i] = 1.0f; counts[i] = 1; }  // self-loop: weight 1.0, one edge
}

__global__ void hist_kernel(const int* __restrict__ dst, const float* __restrict__ ew,
                            float* __restrict__ deg, int* __restrict__ counts, int E) {
    int e = blockIdx.x * blockDim.x + threadIdx.x;
    if (e < E) {
        int d = dst[e];
        atomicAdd(&deg[d], ew[e]);
        atomicAdd(&counts[d], 1);
    }
}

__global__ void dinv_kernel(float* __restrict__ deg, int n) {
    int i = blockIdx.x * blockDim.x + threadIdx.x;
    if (i < n) deg[i] = rsqrtf(deg[i]);  // deg >= 1 always (self-loop weight 1)
}

// --- 3-pass multi-block exclusive scan of counts[0..n) -> row_ptr, cursor ---

// Pass 1: per-block sums (one block = SCAN_CHUNK elements)
__global__ __launch_bounds__(256) void scan_partial_kernel(const int* __restrict__ counts,
                                                           int* __restrict__ block_sums, int n) {
    __shared__ int smem[256];
    int tid = threadIdx.x;
    int base = blockIdx.x * SCAN_CHUNK;
    int sum = 0;
    #pragma unroll
    for (int j = 0; j < SCAN_CHUNK / 256; j++) {
        int idx = base + j * 256 + tid;
        if (idx < n) sum += counts[idx];
    }
    smem[tid] = sum;
    __syncthreads();
    for (int off = 128; off > 0; off >>= 1) {
        if (tid < off) smem[tid] += smem[tid + off];
        __syncthreads();
    }
    if (tid == 0) block_sums[blockIdx.x] = smem[0];
}

// Pass 2: serial exclusive scan of nb (~49) block sums; also writes row_ptr[n] = total
__global__ void scan_blocksums_kernel(int* __restrict__ block_sums, int* __restrict__ row_ptr,
                                      int nb, int n) {
    if (threadIdx.x == 0 && blockIdx.x == 0) {
        int run = 0;
        for (int i = 0; i < nb; i++) { int c = block_sums[i]; block_sums[i] = run; run += c; }
        row_ptr[n] = run;
    }
}

// Pass 3: per-block scan with global offset; writes row_ptr[0..n) and cursor
__global__ __launch_bounds__(256) void scan_final_kernel(const int* __restrict__ counts,
                                                         const int* __restrict__ block_sums,
                                                         int* __restrict__ row_ptr,
                                                         int* __restrict__ cursor, int n) {
    __shared__ int smem[256];
    int tid = threadIdx.x;
    int start = blockIdx.x * SCAN_CHUNK + tid * 8;  // 8 contiguous per thread, 16B-aligned
    int local[8];
    int sum = 0;
    #pragma unroll
    for (int j = 0; j < 8; j++) {
        int idx = start + j;
        local[j] = (idx < n) ? counts[idx] : 0;
        sum += local[j];
    }
    smem[tid] = sum;
    __syncthreads();
    // Hillis-Steele inclusive scan over 256 partials
    for (int off = 1; off < 256; off <<= 1) {
        int add = (tid >= off) ? smem[tid - off] : 0;
        __syncthreads();
        smem[tid] += add;
        __syncthreads();
    }
    int run = block_sums[blockIdx.x] + smem[tid] - sum;  // exclusive prefix of this thread
    #pragma unroll
    for (int j = 0; j < 8; j++) {
        int idx = start + j;
        if (idx < n) {
            row_ptr[idx] = run;
            cursor[idx] = run;
            run += local[j];
        }
    }
}

__global__ void fill_edges_kernel(const int* __restrict__ src, const int* __restrict__ dst,
                                  const float* __restrict__ ew, const float* __restrict__ dinv,
                                  int* __restrict__ cursor, int* __restrict__ col,
                                  float* __restrict__ val, int E) {
    int e = blockIdx.x * blockDim.x + threadIdx.x;
    if (e < E) {
        int s = src[e], d = dst[e];
        int pos = atomicAdd(&cursor[d], 1);
        col[pos] = s;
        val[pos] = dinv[s] * ew[e] * dinv[d];
    }
}

__global__ void fill_loops_kernel(const float* __restrict__ dinv, int* __restrict__ cursor,
                                  int* __restrict__ col, float* __restrict__ val, int n) {
    int i = blockIdx.x * blockDim.x + threadIdx.x;
    if (i < n) {
        int pos = atomicAdd(&cursor[i], 1);
        col[pos] = i;
        val[pos] = dinv[i] * dinv[i];  // self-loop weight 1.0
    }
}

// Tiled fp32 GEMM: C[M,N] = A[M,K] @ B[K,N]. BK=32, 4x4 register tile, 256 threads.
// Requires BM*BN == 4096, K % 32 == 0, N % 4 == 0.
template<int BM, int BN>
__global__ __launch_bounds__(256) void gemm_kernel(const float* __restrict__ A,
                                                   const float* __restrict__ B,
                                                   float* __restrict__ C,
                                                   int M, int K, int N) {
    __shared__ float As[32][BM];   // k-major (A transposed in LDS)
    __shared__ float Bs[32][BN];
    const int tid = threadIdx.x;
    const int block_row = blockIdx.x * BM;
    constexpr int COLG = BN / 4;
    const int tx = tid % COLG;     // col group -> cols tx*4..tx*4+3
    const int ty = tid / COLG;     // row group -> rows ty*4..ty*4+3

    float acc[4][4] = {};

    for (int k0 = 0; k0 < K; k0 += 32) {
        #pragma unroll
        for (int i = tid; i < BM * 8; i += 256) {
            int r = i >> 3, kq = i & 7;
            int rr = block_row + r; if (rr > M - 1) rr = M - 1;
            float4 a = *(const float4*)(A + (size_t)rr * K + k0 + kq * 4);
            As[kq * 4 + 0][r] = a.x;
            As[kq * 4 + 1][r] = a.y;
            As[kq * 4 + 2][r] = a.z;
            As[kq * 4 + 3][r] = a.w;
        }
        #pragma unroll
        for (int i = tid; i < 8 * BN; i += 256) {
            int kk = i / COLG, cq = i % COLG;
            *(float4*)(&Bs[kk][cq * 4]) = *(const float4*)(B + (size_t)(k0 + kk) * N + cq * 4);
        }
        __syncthreads();
        #pragma unroll
        for (int kk = 0; kk < 32; kk++) {
            float4 av = *(const float4*)(&As[kk][ty * 4]);
            float4 bv = *(const float4*)(&Bs[kk][tx * 4]);
            float a[4] = {av.x, av.y, av.z, av.w};
            float b[4] = {bv.x, bv.y, bv.z, bv.w};
            #pragma unroll
            for (int i = 0; i < 4; i++)
                #pragma unroll
                for (int j = 0; j < 4; j++)
                    acc[i][j] += a[i] * b[j];
        }
        __syncthreads();
    }
    #pragma unroll
    for (int i = 0; i < 4; i++) {
        int r = block_row + ty * 4 + i;
        if (r < M) {
            float4 o = make_float4(acc[i][0], acc[i][1], acc[i][2], acc[i][3]);
            *(float4*)(C + (size_t)r * N + tx * 4) = o;
        }
    }
}

// Layer-1 aggregation: one wave per node, 128 feats = float2 per lane. out = relu(agg + b1)
__global__ void agg1_kernel(const float* __restrict__ h, const int* __restrict__ row_ptr,
                            const int* __restrict__ col, const float* __restrict__ val,
                            const float* __restrict__ b1, float* __restrict__ out, int n) {
    int node = blockIdx.x * (blockDim.x >> 6) + (threadIdx.x >> 6);
    int lane = threadIdx.x & 63;
    if (node >= n) return;
    int beg = row_ptr[node], end = row_ptr[node + 1];
    float ax = 0.f, ay = 0.f;
    for (int e = beg; e < end; e++) {
        int s = col[e];
        float v = val[e];
        float2 hv = *(const float2*)(h + (size_t)s * 128 + lane * 2);
        ax += v * hv.x;
        ay += v * hv.y;
    }
    float2 bb = *(const float2*)(b1 + lane * 2);
    ax += bb.x; ay += bb.y;
    ax = ax > 0.f ? ax : 0.f;
    ay = ay > 0.f ? ay : 0.f;
    *(float2*)(out + (size_t)node * 128 + lane * 2) = make_float2(ax, ay);
}

// Layer-2 aggregation + bias + log_softmax: one wave per node, 64 feats = 1 per lane.
__global__ void agg2_kernel(const float* __restrict__ h2, const int* __restrict__ row_ptr,
                            const int* __restrict__ col, const float* __restrict__ val,
                            const float* __restrict__ b2, float* __restrict__ out, int n) {
    int node = blockIdx.x * (blockDim.x >> 6) + (threadIdx.x >> 6);
    int lane = threadIdx.x & 63;
    if (node >= n) return;
    int beg = row_ptr[node], end = row_ptr[node + 1];
    float acc = 0.f;
    for (int e = beg; e < end; e++) {
        acc += val[e] * h2[(size_t)col[e] * 64 + lane];
    }
    acc += b2[lane];
    float m = acc;
    #pragma unroll
    for (int off = 32; off > 0; off >>= 1) m = fmaxf(m, __shfl_xor(m, off));
    float ex = expf(acc - m);
    float s = ex;
    #pragma unroll
    for (int off = 32; off > 0; off >>= 1) s += __shfl_xor(s, off);
    out[(size_t)node * 64 + lane] = acc - m - logf(s);
}

extern "C" void kernel_launch(void* const* d_in, const int* in_sizes, int n_in,
                              void* d_out, int out_size, void* d_ws, size_t ws_size,
                              hipStream_t stream) {
    const float* x  = (const float*)d_in[0];
    const int*   ei = (const int*)d_in[1];
    const float* ew = (const float*)d_in[2];
    const float* W1 = (const float*)d_in[3];
    const float* b1 = (const float*)d_in[4];
    const float* W2 = (const float*)d_in[5];
    const float* b2 = (const float*)d_in[6];
    float* out = (float*)d_out;

    const int N = in_sizes[0] / 256;   // 100000
    const int E = in_sizes[1] / 2;     // 1600000
    const int Et = E + N;              // edges incl. self-loops
    const int* src = ei;
    const int* dst = ei + E;

    char* w = (char*)d_ws;
    size_t off = 0;
    auto carve = [&](size_t bytes) {
        void* p = w + off;
        off = (off + bytes + 255) & ~(size_t)255;
        return p;
    };
    const int NB = (N + SCAN_CHUNK - 1) / SCAN_CHUNK;  // scan blocks (~49)
    float* deg     = (float*)carve((size_t)N * 4);        // becomes dinv in place
    int*   counts  = (int*)  carve((size_t)N * 4);
    int*   row_ptr = (int*)  carve((size_t)(N + 1) * 4);
    int*   cursor  = (int*)  carve((size_t)N * 4);
    int*   bsums   = (int*)  carve((size_t)NB * 4);
    int*   col     = (int*)  carve((size_t)Et * 4);
    float* val     = (float*)carve((size_t)Et * 4);
    float* bufA    = (float*)carve((size_t)N * 128 * 4);  // h = x@W1; later reused as h2
    float* bufB    = (float*)carve((size_t)N * 128 * 4);  // h1 = relu(agg+b1)
    float* bufC    = bufA;                                 // h2 = h1@W2 (aliases bufA, safe)

    const int gN = (N + BLK - 1) / BLK;
    const int gE = (E + BLK - 1) / BLK;

    // 1. CSR build
    init_kernel<<<gN, BLK, 0, stream>>>(deg, counts, N);
    hist_kernel<<<gE, BLK, 0, stream>>>(dst, ew, deg, counts, E);
    dinv_kernel<<<gN, BLK, 0, stream>>>(deg, N);
    scan_partial_kernel<<<NB, 256, 0, stream>>>(counts, bsums, N);
    scan_blocksums_kernel<<<1, 64, 0, stream>>>(bsums, row_ptr, NB, N);
    scan_final_kernel<<<NB, 256, 0, stream>>>(counts, bsums, row_ptr, cursor, N);
    fill_edges_kernel<<<gE, BLK, 0, stream>>>(src, dst, ew, deg, cursor, col, val, E);
    fill_loops_kernel<<<gN, BLK, 0, stream>>>(deg, cursor, col, val, N);

    // 2. Layer 1: h = x @ W1  (100000x256 @ 256x128)
    gemm_kernel<32, 128><<<(N + 31) / 32, 256, 0, stream>>>(x, W1, bufA, N, 256, 128);
    agg1_kernel<<<(N + 3) / 4, 256, 0, stream>>>(bufA, row_ptr, col, val, b1, bufB, N);

    // 3. Layer 2: h2 = h1 @ W2  (100000x128 @ 128x64)
    gemm_kernel<64, 64><<<(N + 63) / 64, 256, 0, stream>>>(bufB, W2, bufC, N, 128, 64);
    agg2_kernel<<<(N + 3) / 4, 256, 0, stream>>>(bufC, row_ptr, col, val, b2, out, N);
}

// Round 3
// 849.150 us; speedup vs baseline: 1.2686x; 1.0274x over previous
//
#include <hip/hip_runtime.h>
#include <hip/hip_fp16.h>

// GCN 2-layer forward: x[N,256] -> GCNConv(W1,b1)+ReLU -> GCNConv(W2,b2) -> log_softmax
// R1: multi-block scan. R2: fp16 intermediate features (h, h1, h2) -> halves the
// gather traffic in both aggregation kernels (the measured roofline limiter).

#define BLK 256
#define SCAN_CHUNK 2048

__global__ void init_kernel(float* __restrict__ deg, int* __restrict__ counts, int n) {
    int i = blockIdx.x * blockDim.x + threadIdx.x;
    if (i < n) { deg[i] = 1.0f; counts[i] = 1; }
}

__global__ void hist_kernel(const int* __restrict__ dst, const float* __restrict__ ew,
                            float* __restrict__ deg, int* __restrict__ counts, int E) {
    int e = blockIdx.x * blockDim.x + threadIdx.x;
    if (e < E) {
        int d = dst[e];
        atomicAdd(&deg[d], ew[e]);
        atomicAdd(&counts[d], 1);
    }
}

__global__ void dinv_kernel(float* __restrict__ deg, int n) {
    int i = blockIdx.x * blockDim.x + threadIdx.x;
    if (i < n) deg[i] = rsqrtf(deg[i]);
}

__global__ __launch_bounds__(256) void scan_partial_kernel(const int* __restrict__ counts,
                                                           int* __restrict__ block_sums, int n) {
    __shared__ int smem[256];
    int tid = threadIdx.x;
    int base = blockIdx.x * SCAN_CHUNK;
    int sum = 0;
    #pragma unroll
    for (int j = 0; j < SCAN_CHUNK / 256; j++) {
        int idx = base + j * 256 + tid;
        if (idx < n) sum += counts[idx];
    }
    smem[tid] = sum;
    __syncthreads();
    for (int off = 128; off > 0; off >>= 1) {
        if (tid < off) smem[tid] += smem[tid + off];
        __syncthreads();
    }
    if (tid == 0) block_sums[blockIdx.x] = smem[0];
}

__global__ void scan_blocksums_kernel(int* __restrict__ block_sums, int* __restrict__ row_ptr,
                                      int nb, int n) {
    if (threadIdx.x == 0 && blockIdx.x == 0) {
        int run = 0;
        for (int i = 0; i < nb; i++) { int c = block_sums[i]; block_sums[i] = run; run += c; }
        row_ptr[n] = run;
    }
}

__global__ __launch_bounds__(256) void scan_final_kernel(const int* __restrict__ counts,
                                                         const int* __restrict__ block_sums,
                                                         int* __restrict__ row_ptr,
                                                         int* __restrict__ cursor, int n) {
    __shared__ int smem[256];
    int tid = threadIdx.x;
    int start = blockIdx.x * SCAN_CHUNK + tid * 8;
    int local[8];
    int sum = 0;
    #pragma unroll
    for (int j = 0; j < 8; j++) {
        int idx = start + j;
        local[j] = (idx < n) ? counts[idx] : 0;
        sum += local[j];
    }
    smem[tid] = sum;
    __syncthreads();
    for (int off = 1; off < 256; off <<= 1) {
        int add = (tid >= off) ? smem[tid - off] : 0;
        __syncthreads();
        smem[tid] += add;
        __syncthreads();
    }
    int run = block_sums[blockIdx.x] + smem[tid] - sum;
    #pragma unroll
    for (int j = 0; j < 8; j++) {
        int idx = start + j;
        if (idx < n) {
            row_ptr[idx] = run;
            cursor[idx] = run;
            run += local[j];
        }
    }
}

__global__ void fill_edges_kernel(const int* __restrict__ src, const int* __restrict__ dst,
                                  const float* __restrict__ ew, const float* __restrict__ dinv,
                                  int* __restrict__ cursor, int* __restrict__ col,
                                  float* __restrict__ val, int E) {
    int e = blockIdx.x * blockDim.x + threadIdx.x;
    if (e < E) {
        int s = src[e], d = dst[e];
        int pos = atomicAdd(&cursor[d], 1);
        col[pos] = s;
        val[pos] = dinv[s] * ew[e] * dinv[d];
    }
}

__global__ void fill_loops_kernel(const float* __restrict__ dinv, int* __restrict__ cursor,
                                  int* __restrict__ col, float* __restrict__ val, int n) {
    int i = blockIdx.x * blockDim.x + threadIdx.x;
    if (i < n) {
        int pos = atomicAdd(&cursor[i], 1);
        col[pos] = i;
        val[pos] = dinv[i] * dinv[i];
    }
}

// ---- dtype helpers for templated GEMM ----
__device__ inline float4 load4(const float* p) { return *(const float4*)p; }
__device__ inline float4 load4(const __half* p) {
    const __half2* q = (const __half2*)p;
    float2 a = __half22float2(q[0]);
    float2 b = __half22float2(q[1]);
    return make_float4(a.x, a.y, b.x, b.y);
}
__device__ inline void store4(float* p, float4 v) { *(float4*)p = v; }
__device__ inline void store4(__half* p, float4 v) {
    __half2 lo = __floats2half2_rn(v.x, v.y);
    __half2 hi = __floats2half2_rn(v.z, v.w);
    __half2* q = (__half2*)p;
    q[0] = lo; q[1] = hi;
}

// Tiled GEMM: C[M,N] = A[M,K] @ B[K,N]. BK=32, 4x4 register tile, 256 threads.
// A: AT (float or __half), B: float, C: CT. Requires BM*BN==4096, K%32==0, N%4==0.
template<int BM, int BN, typename AT, typename CT>
__global__ __launch_bounds__(256) void gemm_kernel(const AT* __restrict__ A,
                                                   const float* __restrict__ B,
                                                   CT* __restrict__ C,
                                                   int M, int K, int N) {
    __shared__ float As[32][BM];   // k-major
    __shared__ float Bs[32][BN];
    const int tid = threadIdx.x;
    const int block_row = blockIdx.x * BM;
    constexpr int COLG = BN / 4;
    const int tx = tid % COLG;
    const int ty = tid / COLG;

    float acc[4][4] = {};

    for (int k0 = 0; k0 < K; k0 += 32) {
        #pragma unroll
        for (int i = tid; i < BM * 8; i += 256) {
            int r = i >> 3, kq = i & 7;
            int rr = block_row + r; if (rr > M - 1) rr = M - 1;
            float4 a = load4(A + (size_t)rr * K + k0 + kq * 4);
            As[kq * 4 + 0][r] = a.x;
            As[kq * 4 + 1][r] = a.y;
            As[kq * 4 + 2][r] = a.z;
            As[kq * 4 + 3][r] = a.w;
        }
        #pragma unroll
        for (int i = tid; i < 8 * BN; i += 256) {
            int kk = i / COLG, cq = i % COLG;
            *(float4*)(&Bs[kk][cq * 4]) = *(const float4*)(B + (size_t)(k0 + kk) * N + cq * 4);
        }
        __syncthreads();
        #pragma unroll
        for (int kk = 0; kk < 32; kk++) {
            float4 av = *(const float4*)(&As[kk][ty * 4]);
            float4 bv = *(const float4*)(&Bs[kk][tx * 4]);
            float a[4] = {av.x, av.y, av.z, av.w};
            float b[4] = {bv.x, bv.y, bv.z, bv.w};
            #pragma unroll
            for (int i = 0; i < 4; i++)
                #pragma unroll
                for (int j = 0; j < 4; j++)
                    acc[i][j] += a[i] * b[j];
        }
        __syncthreads();
    }
    #pragma unroll
    for (int i = 0; i < 4; i++) {
        int r = block_row + ty * 4 + i;
        if (r < M) {
            float4 o = make_float4(acc[i][0], acc[i][1], acc[i][2], acc[i][3]);
            store4(C + (size_t)r * N + tx * 4, o);
        }
    }
}

// Layer-1 aggregation: one wave per node, 128 feats = half2 per lane. out = relu(agg + b1), fp16
__global__ void agg1_kernel(const __half* __restrict__ h, const int* __restrict__ row_ptr,
                            const int* __restrict__ col, const float* __restrict__ val,
                            const float* __restrict__ b1, __half* __restrict__ out, int n) {
    int node = blockIdx.x * (blockDim.x >> 6) + (threadIdx.x >> 6);
    int lane = threadIdx.x & 63;
    if (node >= n) return;
    int beg = row_ptr[node], end = row_ptr[node + 1];
    float ax = 0.f, ay = 0.f;
    for (int e = beg; e < end; e++) {
        int s = col[e];
        float v = val[e];
        float2 hv = __half22float2(*(const __half2*)(h + (size_t)s * 128 + lane * 2));
        ax += v * hv.x;
        ay += v * hv.y;
    }
    float2 bb = *(const float2*)(b1 + lane * 2);
    ax += bb.x; ay += bb.y;
    ax = ax > 0.f ? ax : 0.f;
    ay = ay > 0.f ? ay : 0.f;
    *(__half2*)(out + (size_t)node * 128 + lane * 2) = __floats2half2_rn(ax, ay);
}

// Layer-2 aggregation + bias + log_softmax: one wave per node, 64 feats = 1 per lane.
__global__ void agg2_kernel(const __half* __restrict__ h2, const int* __restrict__ row_ptr,
                            const int* __restrict__ col, const float* __restrict__ val,
                            const float* __restrict__ b2, float* __restrict__ out, int n) {
    int node = blockIdx.x * (blockDim.x >> 6) + (threadIdx.x >> 6);
    int lane = threadIdx.x & 63;
    if (node >= n) return;
    int beg = row_ptr[node], end = row_ptr[node + 1];
    float acc = 0.f;
    for (int e = beg; e < end; e++) {
        acc += val[e] * __half2float(h2[(size_t)col[e] * 64 + lane]);
    }
    acc += b2[lane];
    float m = acc;
    #pragma unroll
    for (int off = 32; off > 0; off >>= 1) m = fmaxf(m, __shfl_xor(m, off));
    float ex = expf(acc - m);
    float s = ex;
    #pragma unroll
    for (int off = 32; off > 0; off >>= 1) s += __shfl_xor(s, off);
    out[(size_t)node * 64 + lane] = acc - m - logf(s);
}

extern "C" void kernel_launch(void* const* d_in, const int* in_sizes, int n_in,
                              void* d_out, int out_size, void* d_ws, size_t ws_size,
                              hipStream_t stream) {
    const float* x  = (const float*)d_in[0];
    const int*   ei = (const int*)d_in[1];
    const float* ew = (const float*)d_in[2];
    const float* W1 = (const float*)d_in[3];
    const float* b1 = (const float*)d_in[4];
    const float* W2 = (const float*)d_in[5];
    const float* b2 = (const float*)d_in[6];
    float* out = (float*)d_out;

    const int N = in_sizes[0] / 256;
    const int E = in_sizes[1] / 2;
    const int Et = E + N;
    const int* src = ei;
    const int* dst = ei + E;

    char* w = (char*)d_ws;
    size_t off = 0;
    auto carve = [&](size_t bytes) {
        void* p = w + off;
        off = (off + bytes + 255) & ~(size_t)255;
        return p;
    };
    const int NB = (N + SCAN_CHUNK - 1) / SCAN_CHUNK;
    float*  deg     = (float*)carve((size_t)N * 4);
    int*    counts  = (int*)  carve((size_t)N * 4);
    int*    row_ptr = (int*)  carve((size_t)(N + 1) * 4);
    int*    cursor  = (int*)  carve((size_t)N * 4);
    int*    bsums   = (int*)  carve((size_t)NB * 4);
    int*    col     = (int*)  carve((size_t)Et * 4);
    float*  val     = (float*)carve((size_t)Et * 4);
    __half* bufA    = (__half*)carve((size_t)N * 128 * 2);  // h fp16; later h2 (aliased)
    __half* bufB    = (__half*)carve((size_t)N * 128 * 2);  // h1 fp16
    __half* bufC    = bufA;                                  // h2 aliases h (safe)

    const int gN = (N + BLK - 1) / BLK;
    const int gE = (E + BLK - 1) / BLK;

    // 1. CSR build
    init_kernel<<<gN, BLK, 0, stream>>>(deg, counts, N);
    hist_kernel<<<gE, BLK, 0, stream>>>(dst, ew, deg, counts, E);
    dinv_kernel<<<gN, BLK, 0, stream>>>(deg, N);
    scan_partial_kernel<<<NB, 256, 0, stream>>>(counts, bsums, N);
    scan_blocksums_kernel<<<1, 64, 0, stream>>>(bsums, row_ptr, NB, N);
    scan_final_kernel<<<NB, 256, 0, stream>>>(counts, bsums, row_ptr, cursor, N);
    fill_edges_kernel<<<gE, BLK, 0, stream>>>(src, dst, ew, deg, cursor, col, val, E);
    fill_loops_kernel<<<gN, BLK, 0, stream>>>(deg, cursor, col, val, N);

    // 2. Layer 1: h = x @ W1 (fp32 in, fp16 out)
    gemm_kernel<32, 128, float, __half><<<(N + 31) / 32, 256, 0, stream>>>(x, W1, bufA, N, 256, 128);
    agg1_kernel<<<(N + 3) / 4, 256, 0, stream>>>(bufA, row_ptr, col, val, b1, bufB, N);

    // 3. Layer 2: h2 = h1 @ W2 (fp16 in, fp16 out)
    gemm_kernel<64, 64, __half, __half><<<(N + 63) / 64, 256, 0, stream>>>(bufB, W2, bufC, N, 128, 64);
    agg2_kernel<<<(N + 3) / 4, 256, 0, stream>>>(bufC, row_ptr, col, val, b2, out, N);
}

// Round 4
// 651.830 us; speedup vs baseline: 1.6527x; 1.3027x over previous
//
#include <hip/hip_runtime.h>
#include <hip/hip_fp16.h>

// GCN 2-layer forward. R1: multi-block scan. R2: fp16 intermediates.
// R3: wide-gather aggregation — 16B/lane, multi-edge-per-wave, 2-deep MLP
// (R2 post-mortem showed agg kernels are latency/issue bound, not BW bound).

#define BLK 256
#define SCAN_CHUNK 2048

__global__ void init_kernel(float* __restrict__ deg, int* __restrict__ counts, int n) {
    int i = blockIdx.x * blockDim.x + threadIdx.x;
    if (i < n) { deg[i] = 1.0f; counts[i] = 1; }
}

__global__ void hist_kernel(const int* __restrict__ dst, const float* __restrict__ ew,
                            float* __restrict__ deg, int* __restrict__ counts, int E) {
    int e = blockIdx.x * blockDim.x + threadIdx.x;
    if (e < E) {
        int d = dst[e];
        atomicAdd(&deg[d], ew[e]);
        atomicAdd(&counts[d], 1);
    }
}

__global__ void dinv_kernel(float* __restrict__ deg, int n) {
    int i = blockIdx.x * blockDim.x + threadIdx.x;
    if (i < n) deg[i] = rsqrtf(deg[i]);
}

__global__ __launch_bounds__(256) void scan_partial_kernel(const int* __restrict__ counts,
                                                           int* __restrict__ block_sums, int n) {
    __shared__ int smem[256];
    int tid = threadIdx.x;
    int base = blockIdx.x * SCAN_CHUNK;
    int sum = 0;
    #pragma unroll
    for (int j = 0; j < SCAN_CHUNK / 256; j++) {
        int idx = base + j * 256 + tid;
        if (idx < n) sum += counts[idx];
    }
    smem[tid] = sum;
    __syncthreads();
    for (int off = 128; off > 0; off >>= 1) {
        if (tid < off) smem[tid] += smem[tid + off];
        __syncthreads();
    }
    if (tid == 0) block_sums[blockIdx.x] = smem[0];
}

__global__ void scan_blocksums_kernel(int* __restrict__ block_sums, int* __restrict__ row_ptr,
                                      int nb, int n) {
    if (threadIdx.x == 0 && blockIdx.x == 0) {
        int run = 0;
        for (int i = 0; i < nb; i++) { int c = block_sums[i]; block_sums[i] = run; run += c; }
        row_ptr[n] = run;
    }
}

__global__ __launch_bounds__(256) void scan_final_kernel(const int* __restrict__ counts,
                                                         const int* __restrict__ block_sums,
                                                         int* __restrict__ row_ptr,
                                                         int* __restrict__ cursor, int n) {
    __shared__ int smem[256];
    int tid = threadIdx.x;
    int start = blockIdx.x * SCAN_CHUNK + tid * 8;
    int local[8];
    int sum = 0;
    #pragma unroll
    for (int j = 0; j < 8; j++) {
        int idx = start + j;
        local[j] = (idx < n) ? counts[idx] : 0;
        sum += local[j];
    }
    smem[tid] = sum;
    __syncthreads();
    for (int off = 1; off < 256; off <<= 1) {
        int add = (tid >= off) ? smem[tid - off] : 0;
        __syncthreads();
        smem[tid] += add;
        __syncthreads();
    }
    int run = block_sums[blockIdx.x] + smem[tid] - sum;
    #pragma unroll
    for (int j = 0; j < 8; j++) {
        int idx = start + j;
        if (idx < n) {
            row_ptr[idx] = run;
            cursor[idx] = run;
            run += local[j];
        }
    }
}

__global__ void fill_edges_kernel(const int* __restrict__ src, const int* __restrict__ dst,
                                  const float* __restrict__ ew, const float* __restrict__ dinv,
                                  int* __restrict__ cursor, int* __restrict__ col,
                                  float* __restrict__ val, int E) {
    int e = blockIdx.x * blockDim.x + threadIdx.x;
    if (e < E) {
        int s = src[e], d = dst[e];
        int pos = atomicAdd(&cursor[d], 1);
        col[pos] = s;
        val[pos] = dinv[s] * ew[e] * dinv[d];
    }
}

__global__ void fill_loops_kernel(const float* __restrict__ dinv, int* __restrict__ cursor,
                                  int* __restrict__ col, float* __restrict__ val, int n) {
    int i = blockIdx.x * blockDim.x + threadIdx.x;
    if (i < n) {
        int pos = atomicAdd(&cursor[i], 1);
        col[pos] = i;
        val[pos] = dinv[i] * dinv[i];
    }
}

// ---- dtype helpers for templated GEMM ----
__device__ inline float4 load4(const float* p) { return *(const float4*)p; }
__device__ inline float4 load4(const __half* p) {
    const __half2* q = (const __half2*)p;
    float2 a = __half22float2(q[0]);
    float2 b = __half22float2(q[1]);
    return make_float4(a.x, a.y, b.x, b.y);
}
__device__ inline void store4(float* p, float4 v) { *(float4*)p = v; }
__device__ inline void store4(__half* p, float4 v) {
    __half2 lo = __floats2half2_rn(v.x, v.y);
    __half2 hi = __floats2half2_rn(v.z, v.w);
    __half2* q = (__half2*)p;
    q[0] = lo; q[1] = hi;
}

// Tiled GEMM: C[M,N] = A[M,K] @ B[K,N]. BK=32, 4x4 register tile, 256 threads.
template<int BM, int BN, typename AT, typename CT>
__global__ __launch_bounds__(256) void gemm_kernel(const AT* __restrict__ A,
                                                   const float* __restrict__ B,
                                                   CT* __restrict__ C,
                                                   int M, int K, int N) {
    __shared__ float As[32][BM];   // k-major
    __shared__ float Bs[32][BN];
    const int tid = threadIdx.x;
    const int block_row = blockIdx.x * BM;
    constexpr int COLG = BN / 4;
    const int tx = tid % COLG;
    const int ty = tid / COLG;

    float acc[4][4] = {};

    for (int k0 = 0; k0 < K; k0 += 32) {
        #pragma unroll
        for (int i = tid; i < BM * 8; i += 256) {
            int r = i >> 3, kq = i & 7;
            int rr = block_row + r; if (rr > M - 1) rr = M - 1;
            float4 a = load4(A + (size_t)rr * K + k0 + kq * 4);
            As[kq * 4 + 0][r] = a.x;
            As[kq * 4 + 1][r] = a.y;
            As[kq * 4 + 2][r] = a.z;
            As[kq * 4 + 3][r] = a.w;
        }
        #pragma unroll
        for (int i = tid; i < 8 * BN; i += 256) {
            int kk = i / COLG, cq = i % COLG;
            *(float4*)(&Bs[kk][cq * 4]) = *(const float4*)(B + (size_t)(k0 + kk) * N + cq * 4);
        }
        __syncthreads();
        #pragma unroll
        for (int kk = 0; kk < 32; kk++) {
            float4 av = *(const float4*)(&As[kk][ty * 4]);
            float4 bv = *(const float4*)(&Bs[kk][tx * 4]);
            float a[4] = {av.x, av.y, av.z, av.w};
            float b[4] = {bv.x, bv.y, bv.z, bv.w};
            #pragma unroll
            for (int i = 0; i < 4; i++)
                #pragma unroll
                for (int j = 0; j < 4; j++)
                    acc[i][j] += a[i] * b[j];
        }
        __syncthreads();
    }
    #pragma unroll
    for (int i = 0; i < 4; i++) {
        int r = block_row + ty * 4 + i;
        if (r < M) {
            float4 o = make_float4(acc[i][0], acc[i][1], acc[i][2], acc[i][3]);
            store4(C + (size_t)r * N + tx * 4, o);
        }
    }
}

// Unpack 8 halfs (uint4) and acc[j] += v * h[j]
__device__ inline void accum8(float* acc, uint4 p, float v) {
    const __half2* q = (const __half2*)&p;
    #pragma unroll
    for (int k = 0; k < 4; k++) {
        float2 f = __half22float2(q[k]);
        acc[2 * k]     += v * f.x;
        acc[2 * k + 1] += v * f.y;
    }
}

// Layer-1 aggregation: one wave per node. 16 lanes/edge x 16B -> 4 edges per
// instruction, 8 edges per trip (2 independent loads). out = relu(agg+b1), fp16.
__global__ void agg1_kernel(const __half* __restrict__ h, const int* __restrict__ row_ptr,
                            const int* __restrict__ col, const float* __restrict__ val,
                            const float* __restrict__ b1, __half* __restrict__ out, int n) {
    int node = blockIdx.x * (blockDim.x >> 6) + (threadIdx.x >> 6);
    int lane = threadIdx.x & 63;
    if (node >= n) return;
    int g = lane >> 4;   // edge slot 0..3
    int l = lane & 15;   // feats 8l..8l+7
    int beg = row_ptr[node], end = row_ptr[node + 1];
    float acc[8] = {};
    const __half* hb = h + l * 8;
    for (int e0 = beg; e0 < end; e0 += 8) {
        int eA = e0 + g, eB = e0 + 4 + g;
        int cA = min(eA, end - 1), cB = min(eB, end - 1);
        int sA = col[cA], sB = col[cB];
        float vA = (eA < end) ? val[cA] : 0.f;
        float vB = (eB < end) ? val[cB] : 0.f;
        uint4 pA = *(const uint4*)(hb + (size_t)sA * 128);
        uint4 pB = *(const uint4*)(hb + (size_t)sB * 128);
        accum8(acc, pA, vA);
        accum8(acc, pB, vB);
    }
    #pragma unroll
    for (int j = 0; j < 8; j++) {
        acc[j] += __shfl_xor(acc[j], 32);
        acc[j] += __shfl_xor(acc[j], 16);
    }
    if (g == 0) {
        float4 b0 = *(const float4*)(b1 + l * 8);
        float4 b1v = *(const float4*)(b1 + l * 8 + 4);
        float r[8] = {acc[0] + b0.x, acc[1] + b0.y, acc[2] + b0.z, acc[3] + b0.w,
                      acc[4] + b1v.x, acc[5] + b1v.y, acc[6] + b1v.z, acc[7] + b1v.w};
        #pragma unroll
        for (int j = 0; j < 8; j++) r[j] = r[j] > 0.f ? r[j] : 0.f;
        __half2 o[4];
        #pragma unroll
        for (int k = 0; k < 4; k++) o[k] = __floats2half2_rn(r[2 * k], r[2 * k + 1]);
        *(uint4*)(out + (size_t)node * 128 + l * 8) = *(uint4*)o;
    }
}

// Layer-2 aggregation + log_softmax: 8 lanes/edge x 16B -> 8 edges per
// instruction, 16 per trip. Output fp32 [N,64].
__global__ void agg2_kernel(const __half* __restrict__ h2, const int* __restrict__ row_ptr,
                            const int* __restrict__ col, const float* __restrict__ val,
                            const float* __restrict__ b2, float* __restrict__ out, int n) {
    int node = blockIdx.x * (blockDim.x >> 6) + (threadIdx.x >> 6);
    int lane = threadIdx.x & 63;
    if (node >= n) return;
    int g = lane >> 3;  // edge slot 0..7
    int l = lane & 7;   // feats 8l..8l+7
    int beg = row_ptr[node], end = row_ptr[node + 1];
    float acc[8] = {};
    const __half* hb = h2 + l * 8;
    for (int e0 = beg; e0 < end; e0 += 16) {
        int eA = e0 + g, eB = e0 + 8 + g;
        int cA = min(eA, end - 1), cB = min(eB, end - 1);
        int sA = col[cA], sB = col[cB];
        float vA = (eA < end) ? val[cA] : 0.f;
        float vB = (eB < end) ? val[cB] : 0.f;
        uint4 pA = *(const uint4*)(hb + (size_t)sA * 64);
        uint4 pB = *(const uint4*)(hb + (size_t)sB * 64);
        accum8(acc, pA, vA);
        accum8(acc, pB, vB);
    }
    #pragma unroll
    for (int j = 0; j < 8; j++) {
        acc[j] += __shfl_xor(acc[j], 32);
        acc[j] += __shfl_xor(acc[j], 16);
        acc[j] += __shfl_xor(acc[j], 8);
    }
    // + bias
    float4 b0 = *(const float4*)(b2 + l * 8);
    float4 b1v = *(const float4*)(b2 + l * 8 + 4);
    acc[0] += b0.x;  acc[1] += b0.y;  acc[2] += b0.z;  acc[3] += b0.w;
    acc[4] += b1v.x; acc[5] += b1v.y; acc[6] += b1v.z; acc[7] += b1v.w;
    // log_softmax over 64 values (8 comps x 8 l-groups; all 8-lane blocks identical)
    float m = acc[0];
    #pragma unroll
    for (int j = 1; j < 8; j++) m = fmaxf(m, acc[j]);
    #pragma unroll
    for (int off = 1; off < 8; off <<= 1) m = fmaxf(m, __shfl_xor(m, off));
    float s = 0.f;
    #pragma unroll
    for (int j = 0; j < 8; j++) s += expf(acc[j] - m);
    #pragma unroll
    for (int off = 1; off < 8; off <<= 1) s += __shfl_xor(s, off);
    float ls = m + logf(s);
    if (g == 0) {
        float* op = out + (size_t)node * 64 + l * 8;
        *(float4*)(op)     = make_float4(acc[0] - ls, acc[1] - ls, acc[2] - ls, acc[3] - ls);
        *(float4*)(op + 4) = make_float4(acc[4] - ls, acc[5] - ls, acc[6] - ls, acc[7] - ls);
    }
}

extern "C" void kernel_launch(void* const* d_in, const int* in_sizes, int n_in,
                              void* d_out, int out_size, void* d_ws, size_t ws_size,
                              hipStream_t stream) {
    const float* x  = (const float*)d_in[0];
    const int*   ei = (const int*)d_in[1];
    const float* ew = (const float*)d_in[2];
    const float* W1 = (const float*)d_in[3];
    const float* b1 = (const float*)d_in[4];
    const float* W2 = (const float*)d_in[5];
    const float* b2 = (const float*)d_in[6];
    float* out = (float*)d_out;

    const int N = in_sizes[0] / 256;
    const int E = in_sizes[1] / 2;
    const int Et = E + N;
    const int* src = ei;
    const int* dst = ei + E;

    char* w = (char*)d_ws;
    size_t off = 0;
    auto carve = [&](size_t bytes) {
        void* p = w + off;
        off = (off + bytes + 255) & ~(size_t)255;
        return p;
    };
    const int NB = (N + SCAN_CHUNK - 1) / SCAN_CHUNK;
    float*  deg     = (float*)carve((size_t)N * 4);
    int*    counts  = (int*)  carve((size_t)N * 4);
    int*    row_ptr = (int*)  carve((size_t)(N + 1) * 4);
    int*    cursor  = (int*)  carve((size_t)N * 4);
    int*    bsums   = (int*)  carve((size_t)NB * 4);
    int*    col     = (int*)  carve((size_t)Et * 4);
    float*  val     = (float*)carve((size_t)Et * 4);
    __half* bufA    = (__half*)carve((size_t)N * 128 * 2);  // h fp16; later h2 (aliased)
    __half* bufB    = (__half*)carve((size_t)N * 128 * 2);  // h1 fp16
    __half* bufC    = bufA;

    const int gN = (N + BLK - 1) / BLK;
    const int gE = (E + BLK - 1) / BLK;

    // 1. CSR build
    init_kernel<<<gN, BLK, 0, stream>>>(deg, counts, N);
    hist_kernel<<<gE, BLK, 0, stream>>>(dst, ew, deg, counts, E);
    dinv_kernel<<<gN, BLK, 0, stream>>>(deg, N);
    scan_partial_kernel<<<NB, 256, 0, stream>>>(counts, bsums, N);
    scan_blocksums_kernel<<<1, 64, 0, stream>>>(bsums, row_ptr, NB, N);
    scan_final_kernel<<<NB, 256, 0, stream>>>(counts, bsums, row_ptr, cursor, N);
    fill_edges_kernel<<<gE, BLK, 0, stream>>>(src, dst, ew, deg, cursor, col, val, E);
    fill_loops_kernel<<<gN, BLK, 0, stream>>>(deg, cursor, col, val, N);

    // 2. Layer 1: h = x @ W1 (fp32 in, fp16 out)
    gemm_kernel<32, 128, float, __half><<<(N + 31) / 32, 256, 0, stream>>>(x, W1, bufA, N, 256, 128);
    agg1_kernel<<<(N + 3) / 4, 256, 0, stream>>>(bufA, row_ptr, col, val, b1, bufB, N);

    // 3. Layer 2: h2 = h1 @ W2 (fp16 in, fp16 out)
    gemm_kernel<64, 64, __half, __half><<<(N + 63) / 64, 256, 0, stream>>>(bufB, W2, bufC, N, 128, 64);
    agg2_kernel<<<(N + 3) / 4, 256, 0, stream>>>(bufC, row_ptr, col, val, b2, out, N);
}

// Round 5
// 581.186 us; speedup vs baseline: 1.8536x; 1.1216x over previous
//
#include <hip/hip_runtime.h>
#include <hip/hip_fp16.h>

// GCN 2-layer forward. R1: multi-block scan. R2: fp16 intermediates.
// R3: wide-gather aggregation. R4: packed 64-bit histogram atomic (halves
// memory-side atomic traffic) + fp16 MFMA GEMMs (16x16x32_f16).

#define BLK 256
#define SCAN_CHUNK 2048

typedef _Float16 half8 __attribute__((ext_vector_type(8)));
typedef float f32x4 __attribute__((ext_vector_type(4)));

// degcnt[i] = (count << 52) + sum(w * 2^32)
__global__ void init_kernel(unsigned long long* __restrict__ degcnt, int n) {
    int i = blockIdx.x * blockDim.x + threadIdx.x;
    if (i < n) degcnt[i] = (1ULL << 52) + (1ULL << 32);  // self-loop: count 1, weight 1.0
}

__global__ void hist_kernel(const int* __restrict__ dst, const float* __restrict__ ew,
                            unsigned long long* __restrict__ degcnt, int E) {
    int e = blockIdx.x * blockDim.x + threadIdx.x;
    if (e < E) {
        unsigned long long pack = (1ULL << 52) +
            (unsigned long long)(ew[e] * 4294967296.0f);
        atomicAdd(&degcnt[dst[e]], pack);
    }
}

// unpack: counts + dinv = rsqrt(weighted degree)
__global__ void dinv_kernel(const unsigned long long* __restrict__ degcnt,
                            int* __restrict__ counts, float* __restrict__ dinv, int n) {
    int i = blockIdx.x * blockDim.x + threadIdx.x;
    if (i < n) {
        unsigned long long v = degcnt[i];
        counts[i] = (int)(v >> 52);
        float wsum = (float)(v & ((1ULL << 52) - 1)) * (1.0f / 4294967296.0f);
        dinv[i] = rsqrtf(wsum);
    }
}

__global__ __launch_bounds__(256) void scan_partial_kernel(const int* __restrict__ counts,
                                                           int* __restrict__ block_sums, int n) {
    __shared__ int smem[256];
    int tid = threadIdx.x;
    int base = blockIdx.x * SCAN_CHUNK;
    int sum = 0;
    #pragma unroll
    for (int j = 0; j < SCAN_CHUNK / 256; j++) {
        int idx = base + j * 256 + tid;
        if (idx < n) sum += counts[idx];
    }
    smem[tid] = sum;
    __syncthreads();
    for (int off = 128; off > 0; off >>= 1) {
        if (tid < off) smem[tid] += smem[tid + off];
        __syncthreads();
    }
    if (tid == 0) block_sums[blockIdx.x] = smem[0];
}

__global__ void scan_blocksums_kernel(int* __restrict__ block_sums, int* __restrict__ row_ptr,
                                      int nb, int n) {
    if (threadIdx.x == 0 && blockIdx.x == 0) {
        int run = 0;
        for (int i = 0; i < nb; i++) { int c = block_sums[i]; block_sums[i] = run; run += c; }
        row_ptr[n] = run;
    }
}

__global__ __launch_bounds__(256) void scan_final_kernel(const int* __restrict__ counts,
                                                         const int* __restrict__ block_sums,
                                                         int* __restrict__ row_ptr,
                                                         int* __restrict__ cursor, int n) {
    __shared__ int smem[256];
    int tid = threadIdx.x;
    int start = blockIdx.x * SCAN_CHUNK + tid * 8;
    int local[8];
    int sum = 0;
    #pragma unroll
    for (int j = 0; j < 8; j++) {
        int idx = start + j;
        local[j] = (idx < n) ? counts[idx] : 0;
        sum += local[j];
    }
    smem[tid] = sum;
    __syncthreads();
    for (int off = 1; off < 256; off <<= 1) {
        int add = (tid >= off) ? smem[tid - off] : 0;
        __syncthreads();
        smem[tid] += add;
        __syncthreads();
    }
    int run = block_sums[blockIdx.x] + smem[tid] - sum;
    #pragma unroll
    for (int j = 0; j < 8; j++) {
        int idx = start + j;
        if (idx < n) {
            row_ptr[idx] = run;
            cursor[idx] = run;
            run += local[j];
        }
    }
}

__global__ void fill_edges_kernel(const int* __restrict__ src, const int* __restrict__ dst,
                                  const float* __restrict__ ew, const float* __restrict__ dinv,
                                  int* __restrict__ cursor, int* __restrict__ col,
                                  float* __restrict__ val, int E) {
    int e = blockIdx.x * blockDim.x + threadIdx.x;
    if (e < E) {
        int s = src[e], d = dst[e];
        int pos = atomicAdd(&cursor[d], 1);
        col[pos] = s;
        val[pos] = dinv[s] * ew[e] * dinv[d];
    }
}

__global__ void fill_loops_kernel(const float* __restrict__ dinv, int* __restrict__ cursor,
                                  int* __restrict__ col, float* __restrict__ val, int n) {
    int i = blockIdx.x * blockDim.x + threadIdx.x;
    if (i < n) {
        int pos = atomicAdd(&cursor[i], 1);
        col[pos] = i;
        val[pos] = dinv[i] * dinv[i];
    }
}

// W[K][NN] fp32 -> WT[NN][K] fp16
__global__ void convert_wT_kernel(const float* __restrict__ W, _Float16* __restrict__ WT,
                                  int K, int NN) {
    int i = blockIdx.x * blockDim.x + threadIdx.x;
    if (i < K * NN) {
        int k = i / NN, nn = i % NN;
        WT[(size_t)nn * K + k] = (_Float16)W[i];
    }
}

// MFMA GEMM: C[M,NN] = A[M,K] @ WT[NN,K]^T, fp16 inputs, fp16 out.
// Block = 256 thr = 4 waves; block tile 64 rows x NN cols; wave = 16 rows.
// K in {256,128}, NN = NT*16.
template<int K, int NT, typename AT>
__global__ __launch_bounds__(256) void gemm_mfma_kernel(const AT* __restrict__ A,
                                                        const _Float16* __restrict__ WT,
                                                        _Float16* __restrict__ C, int M) {
    constexpr int NN = NT * 16;
    constexpr int LDA = K + 8;                 // pad: +16B -> bank shift 4/row
    __shared__ _Float16 As[64][LDA];
    const int tid = threadIdx.x;
    const int wave = tid >> 6;
    const int lane = tid & 63;
    const int quad = lane >> 4;
    const int nl = lane & 15;
    const int block_row = blockIdx.x * 64;

    // ---- stage A (64 x K) into LDS as fp16 ----
    if constexpr (sizeof(AT) == 4) {           // fp32 source: float4 loads, half4 stores
        #pragma unroll
        for (int i = tid; i < 64 * K / 4; i += 256) {
            int r = i / (K / 4), c4 = i % (K / 4);
            int rr = block_row + r; if (rr > M - 1) rr = M - 1;
            float4 a = *(const float4*)(A + (size_t)rr * K + c4 * 4);
            _Float16 h4[4] = {(_Float16)a.x, (_Float16)a.y, (_Float16)a.z, (_Float16)a.w};
            *(uint2*)(&As[r][c4 * 4]) = *(uint2*)h4;
        }
    } else {                                   // fp16 source: uint4 loads/stores
        #pragma unroll
        for (int i = tid; i < 64 * K / 8; i += 256) {
            int r = i / (K / 8), c8 = i % (K / 8);
            int rr = block_row + r; if (rr > M - 1) rr = M - 1;
            uint4 a = *(const uint4*)(A + (size_t)rr * K + c8 * 8);
            *(uint4*)(&As[r][c8 * 8]) = a;
        }
    }
    __syncthreads();

    // ---- MFMA main loop ----
    f32x4 acc[NT] = {};
    const int m = wave * 16 + nl;              // A row within block tile (A[m][k])
    #pragma unroll
    for (int k0 = 0; k0 < K; k0 += 32) {
        half8 af = *(const half8*)(&As[m][k0 + quad * 8]);
        #pragma unroll
        for (int t = 0; t < NT; t++) {
            half8 bf = *(const half8*)(WT + (size_t)(t * 16 + nl) * K + k0 + quad * 8);
            acc[t] = __builtin_amdgcn_mfma_f32_16x16x32_f16(af, bf, acc[t], 0, 0, 0);
        }
    }

    // ---- epilogue: D[row=quad*4+r][col=nl] per tile ----
    #pragma unroll
    for (int t = 0; t < NT; t++) {
        #pragma unroll
        for (int r = 0; r < 4; r++) {
            int grow = block_row + wave * 16 + quad * 4 + r;
            if (grow < M) C[(size_t)grow * NN + t * 16 + nl] = (_Float16)acc[t][r];
        }
    }
}

// Unpack 8 halfs (uint4) and acc[j] += v * h[j]
__device__ inline void accum8(float* acc, uint4 p, float v) {
    const __half2* q = (const __half2*)&p;
    #pragma unroll
    for (int k = 0; k < 4; k++) {
        float2 f = __half22float2(q[k]);
        acc[2 * k]     += v * f.x;
        acc[2 * k + 1] += v * f.y;
    }
}

// Layer-1 aggregation: one wave per node. 16 lanes/edge x 16B -> 4 edges/inst,
// 8 edges/trip. out = relu(agg+b1), fp16.
__global__ void agg1_kernel(const __half* __restrict__ h, const int* __restrict__ row_ptr,
                            const int* __restrict__ col, const float* __restrict__ val,
                            const float* __restrict__ b1, __half* __restrict__ out, int n) {
    int node = blockIdx.x * (blockDim.x >> 6) + (threadIdx.x >> 6);
    int lane = threadIdx.x & 63;
    if (node >= n) return;
    int g = lane >> 4;
    int l = lane & 15;
    int beg = row_ptr[node], end = row_ptr[node + 1];
    float acc[8] = {};
    const __half* hb = h + l * 8;
    for (int e0 = beg; e0 < end; e0 += 8) {
        int eA = e0 + g, eB = e0 + 4 + g;
        int cA = min(eA, end - 1), cB = min(eB, end - 1);
        int sA = col[cA], sB = col[cB];
        float vA = (eA < end) ? val[cA] : 0.f;
        float vB = (eB < end) ? val[cB] : 0.f;
        uint4 pA = *(const uint4*)(hb + (size_t)sA * 128);
        uint4 pB = *(const uint4*)(hb + (size_t)sB * 128);
        accum8(acc, pA, vA);
        accum8(acc, pB, vB);
    }
    #pragma unroll
    for (int j = 0; j < 8; j++) {
        acc[j] += __shfl_xor(acc[j], 32);
        acc[j] += __shfl_xor(acc[j], 16);
    }
    if (g == 0) {
        float4 b0 = *(const float4*)(b1 + l * 8);
        float4 b1v = *(const float4*)(b1 + l * 8 + 4);
        float r[8] = {acc[0] + b0.x, acc[1] + b0.y, acc[2] + b0.z, acc[3] + b0.w,
                      acc[4] + b1v.x, acc[5] + b1v.y, acc[6] + b1v.z, acc[7] + b1v.w};
        #pragma unroll
        for (int j = 0; j < 8; j++) r[j] = r[j] > 0.f ? r[j] : 0.f;
        __half2 o[4];
        #pragma unroll
        for (int k = 0; k < 4; k++) o[k] = __floats2half2_rn(r[2 * k], r[2 * k + 1]);
        *(uint4*)(out + (size_t)node * 128 + l * 8) = *(uint4*)o;
    }
}

// Layer-2 aggregation + log_softmax: 8 lanes/edge x 16B -> 8 edges/inst.
__global__ void agg2_kernel(const __half* __restrict__ h2, const int* __restrict__ row_ptr,
                            const int* __restrict__ col, const float* __restrict__ val,
                            const float* __restrict__ b2, float* __restrict__ out, int n) {
    int node = blockIdx.x * (blockDim.x >> 6) + (threadIdx.x >> 6);
    int lane = threadIdx.x & 63;
    if (node >= n) return;
    int g = lane >> 3;
    int l = lane & 7;
    int beg = row_ptr[node], end = row_ptr[node + 1];
    float acc[8] = {};
    const __half* hb = h2 + l * 8;
    for (int e0 = beg; e0 < end; e0 += 16) {
        int eA = e0 + g, eB = e0 + 8 + g;
        int cA = min(eA, end - 1), cB = min(eB, end - 1);
        int sA = col[cA], sB = col[cB];
        float vA = (eA < end) ? val[cA] : 0.f;
        float vB = (eB < end) ? val[cB] : 0.f;
        uint4 pA = *(const uint4*)(hb + (size_t)sA * 64);
        uint4 pB = *(const uint4*)(hb + (size_t)sB * 64);
        accum8(acc, pA, vA);
        accum8(acc, pB, vB);
    }
    #pragma unroll
    for (int j = 0; j < 8; j++) {
        acc[j] += __shfl_xor(acc[j], 32);
        acc[j] += __shfl_xor(acc[j], 16);
        acc[j] += __shfl_xor(acc[j], 8);
    }
    float4 b0 = *(const float4*)(b2 + l * 8);
    float4 b1v = *(const float4*)(b2 + l * 8 + 4);
    acc[0] += b0.x;  acc[1] += b0.y;  acc[2] += b0.z;  acc[3] += b0.w;
    acc[4] += b1v.x; acc[5] += b1v.y; acc[6] += b1v.z; acc[7] += b1v.w;
    float m = acc[0];
    #pragma unroll
    for (int j = 1; j < 8; j++) m = fmaxf(m, acc[j]);
    #pragma unroll
    for (int off = 1; off < 8; off <<= 1) m = fmaxf(m, __shfl_xor(m, off));
    float s = 0.f;
    #pragma unroll
    for (int j = 0; j < 8; j++) s += expf(acc[j] - m);
    #pragma unroll
    for (int off = 1; off < 8; off <<= 1) s += __shfl_xor(s, off);
    float ls = m + logf(s);
    if (g == 0) {
        float* op = out + (size_t)node * 64 + l * 8;
        *(float4*)(op)     = make_float4(acc[0] - ls, acc[1] - ls, acc[2] - ls, acc[3] - ls);
        *(float4*)(op + 4) = make_float4(acc[4] - ls, acc[5] - ls, acc[6] - ls, acc[7] - ls);
    }
}

extern "C" void kernel_launch(void* const* d_in, const int* in_sizes, int n_in,
                              void* d_out, int out_size, void* d_ws, size_t ws_size,
                              hipStream_t stream) {
    const float* x  = (const float*)d_in[0];
    const int*   ei = (const int*)d_in[1];
    const float* ew = (const float*)d_in[2];
    const float* W1 = (const float*)d_in[3];
    const float* b1 = (const float*)d_in[4];
    const float* W2 = (const float*)d_in[5];
    const float* b2 = (const float*)d_in[6];
    float* out = (float*)d_out;

    const int N = in_sizes[0] / 256;
    const int E = in_sizes[1] / 2;
    const int Et = E + N;
    const int* src = ei;
    const int* dst = ei + E;

    char* w = (char*)d_ws;
    size_t off = 0;
    auto carve = [&](size_t bytes) {
        void* p = w + off;
        off = (off + bytes + 255) & ~(size_t)255;
        return p;
    };
    const int NB = (N + SCAN_CHUNK - 1) / SCAN_CHUNK;
    unsigned long long* degcnt = (unsigned long long*)carve((size_t)N * 8);
    float*    dinv    = (float*)carve((size_t)N * 4);
    int*      counts  = (int*)  carve((size_t)N * 4);
    int*      row_ptr = (int*)  carve((size_t)(N + 1) * 4);
    int*      cursor  = (int*)  carve((size_t)N * 4);
    int*      bsums   = (int*)  carve((size_t)NB * 4);
    int*      col     = (int*)  carve((size_t)Et * 4);
    float*    val     = (float*)carve((size_t)Et * 4);
    _Float16* w1t     = (_Float16*)carve((size_t)256 * 128 * 2);
    _Float16* w2t     = (_Float16*)carve((size_t)128 * 64 * 2);
    _Float16* bufA    = (_Float16*)carve((size_t)N * 128 * 2);  // h; later h2 (aliased)
    _Float16* bufB    = (_Float16*)carve((size_t)N * 128 * 2);  // h1
    _Float16* bufC    = bufA;

    const int gN = (N + BLK - 1) / BLK;
    const int gE = (E + BLK - 1) / BLK;

    // 1. CSR build
    init_kernel<<<gN, BLK, 0, stream>>>(degcnt, N);
    hist_kernel<<<gE, BLK, 0, stream>>>(dst, ew, degcnt, E);
    dinv_kernel<<<gN, BLK, 0, stream>>>(degcnt, counts, dinv, N);
    scan_partial_kernel<<<NB, 256, 0, stream>>>(counts, bsums, N);
    scan_blocksums_kernel<<<1, 64, 0, stream>>>(bsums, row_ptr, NB, N);
    scan_final_kernel<<<NB, 256, 0, stream>>>(counts, bsums, row_ptr, cursor, N);
    fill_edges_kernel<<<gE, BLK, 0, stream>>>(src, dst, ew, dinv, cursor, col, val, E);
    fill_loops_kernel<<<gN, BLK, 0, stream>>>(dinv, cursor, col, val, N);

    // weight transposes (tiny)
    convert_wT_kernel<<<(256 * 128 + 255) / 256, 256, 0, stream>>>(W1, w1t, 256, 128);
    convert_wT_kernel<<<(128 * 64 + 255) / 256, 256, 0, stream>>>(W2, w2t, 128, 64);

    // 2. Layer 1: h = x @ W1 (MFMA fp16), then h1 = relu(agg(h)+b1)
    gemm_mfma_kernel<256, 8, float><<<(N + 63) / 64, 256, 0, stream>>>(x, w1t, bufA, N);
    agg1_kernel<<<(N + 3) / 4, 256, 0, stream>>>((const __half*)bufA, row_ptr, col, val, b1,
                                                 (__half*)bufB, N);

    // 3. Layer 2: h2 = h1 @ W2 (MFMA fp16), then out = log_softmax(agg(h2)+b2)
    gemm_mfma_kernel<128, 4, _Float16><<<(N + 63) / 64, 256, 0, stream>>>(bufB, w2t, bufC, N);
    agg2_kernel<<<(N + 3) / 4, 256, 0, stream>>>((const __half*)bufC, row_ptr, col, val, b2,
                                                 out, N);
}

// Round 6
// 572.318 us; speedup vs baseline: 1.8823x; 1.0155x over previous
//
#include <hip/hip_runtime.h>
#include <hip/hip_fp16.h>

// GCN 2-layer forward. R1: multi-block scan. R2: fp16 intermediates.
// R3: wide-gather aggregation. R4: packed 64-bit histogram atomic + fp16 MFMA GEMMs.
// R5: normalization reformulated (h' = dinv*h in GEMM epilogue, *dinv[i] in agg)
//     -> fill_edges writes one packed 8B {src, ew}; self-loops written in
//     scan_final (no fill_loops kernel, no atomic); degcnt zeroed via memsetAsync.

#define BLK 256
#define SCAN_CHUNK 2048

typedef _Float16 half8 __attribute__((ext_vector_type(8)));
typedef float f32x4 __attribute__((ext_vector_type(4)));

__global__ void hist_kernel(const int* __restrict__ dst, const float* __restrict__ ew,
                            unsigned long long* __restrict__ degcnt, int E) {
    int e = blockIdx.x * blockDim.x + threadIdx.x;
    if (e < E) {
        unsigned long long pack = (1ULL << 52) +
            (unsigned long long)(ew[e] * 4294967296.0f);
        atomicAdd(&degcnt[dst[e]], pack);
    }
}

// unpack (+ self-loop: count+1, weight+1.0): counts, dinv = rsqrt(weighted degree)
__global__ void dinv_kernel(const unsigned long long* __restrict__ degcnt,
                            int* __restrict__ counts, float* __restrict__ dinv, int n) {
    int i = blockIdx.x * blockDim.x + threadIdx.x;
    if (i < n) {
        unsigned long long v = degcnt[i];
        counts[i] = (int)(v >> 52) + 1;
        float wsum = (float)(v & ((1ULL << 52) - 1)) * (1.0f / 4294967296.0f) + 1.0f;
        dinv[i] = rsqrtf(wsum);
    }
}

__global__ __launch_bounds__(256) void scan_partial_kernel(const int* __restrict__ counts,
                                                           int* __restrict__ block_sums, int n) {
    __shared__ int smem[256];
    int tid = threadIdx.x;
    int base = blockIdx.x * SCAN_CHUNK;
    int sum = 0;
    #pragma unroll
    for (int j = 0; j < SCAN_CHUNK / 256; j++) {
        int idx = base + j * 256 + tid;
        if (idx < n) sum += counts[idx];
    }
    smem[tid] = sum;
    __syncthreads();
    for (int off = 128; off > 0; off >>= 1) {
        if (tid < off) smem[tid] += smem[tid + off];
        __syncthreads();
    }
    if (tid == 0) block_sums[blockIdx.x] = smem[0];
}

__global__ void scan_blocksums_kernel(int* __restrict__ block_sums, int* __restrict__ row_ptr,
                                      int nb, int n) {
    if (threadIdx.x == 0 && blockIdx.x == 0) {
        int run = 0;
        for (int i = 0; i < nb; i++) { int c = block_sums[i]; block_sums[i] = run; run += c; }
        row_ptr[n] = run;
    }
}

// Per-block scan; writes row_ptr, cursor (=row_ptr+1: slot 0 reserved for the
// self-loop), and the self-loop edge {i, 1.0f} at edges[row_ptr[i]].
__global__ __launch_bounds__(256) void scan_final_kernel(const int* __restrict__ counts,
                                                         const int* __restrict__ block_sums,
                                                         int* __restrict__ row_ptr,
                                                         int* __restrict__ cursor,
                                                         uint2* __restrict__ edges, int n) {
    __shared__ int smem[256];
    int tid = threadIdx.x;
    int start = blockIdx.x * SCAN_CHUNK + tid * 8;
    int local[8];
    int sum = 0;
    #pragma unroll
    for (int j = 0; j < 8; j++) {
        int idx = start + j;
        local[j] = (idx < n) ? counts[idx] : 0;
        sum += local[j];
    }
    smem[tid] = sum;
    __syncthreads();
    for (int off = 1; off < 256; off <<= 1) {
        int add = (tid >= off) ? smem[tid - off] : 0;
        __syncthreads();
        smem[tid] += add;
        __syncthreads();
    }
    int run = block_sums[blockIdx.x] + smem[tid] - sum;
    #pragma unroll
    for (int j = 0; j < 8; j++) {
        int idx = start + j;
        if (idx < n) {
            row_ptr[idx] = run;
            cursor[idx] = run + 1;
            edges[run] = make_uint2((unsigned)idx, __float_as_uint(1.0f));  // self-loop
            run += local[j];
        }
    }
}

// One packed 8B write per edge: {src, raw ew}. No dinv needed (reformulated).
__global__ void fill_edges_kernel(const int* __restrict__ src, const int* __restrict__ dst,
                                  const float* __restrict__ ew, int* __restrict__ cursor,
                                  uint2* __restrict__ edges, int E) {
    int e = blockIdx.x * blockDim.x + threadIdx.x;
    if (e < E) {
        int d = dst[e];
        int pos = atomicAdd(&cursor[d], 1);
        edges[pos] = make_uint2((unsigned)src[e], __float_as_uint(ew[e]));
    }
}

// W[K][NN] fp32 -> WT[NN][K] fp16
__global__ void convert_wT_kernel(const float* __restrict__ W, _Float16* __restrict__ WT,
                                  int K, int NN) {
    int i = blockIdx.x * blockDim.x + threadIdx.x;
    if (i < K * NN) {
        int k = i / NN, nn = i % NN;
        WT[(size_t)nn * K + k] = (_Float16)W[i];
    }
}

// MFMA GEMM: C[M,NN] = scale[m] * (A[M,K] @ WT[NN,K]^T), fp16 out.
// Block = 256 thr = 4 waves; block tile 64 rows; K in {256,128}, NN = NT*16.
template<int K, int NT, typename AT>
__global__ __launch_bounds__(256) void gemm_mfma_kernel(const AT* __restrict__ A,
                                                        const _Float16* __restrict__ WT,
                                                        const float* __restrict__ scale,
                                                        _Float16* __restrict__ C, int M) {
    constexpr int NN = NT * 16;
    constexpr int LDA = K + 8;
    __shared__ _Float16 As[64][LDA];
    const int tid = threadIdx.x;
    const int wave = tid >> 6;
    const int lane = tid & 63;
    const int quad = lane >> 4;
    const int nl = lane & 15;
    const int block_row = blockIdx.x * 64;

    if constexpr (sizeof(AT) == 4) {
        #pragma unroll
        for (int i = tid; i < 64 * K / 4; i += 256) {
            int r = i / (K / 4), c4 = i % (K / 4);
            int rr = block_row + r; if (rr > M - 1) rr = M - 1;
            float4 a = *(const float4*)(A + (size_t)rr * K + c4 * 4);
            _Float16 h4[4] = {(_Float16)a.x, (_Float16)a.y, (_Float16)a.z, (_Float16)a.w};
            *(uint2*)(&As[r][c4 * 4]) = *(uint2*)h4;
        }
    } else {
        #pragma unroll
        for (int i = tid; i < 64 * K / 8; i += 256) {
            int r = i / (K / 8), c8 = i % (K / 8);
            int rr = block_row + r; if (rr > M - 1) rr = M - 1;
            uint4 a = *(const uint4*)(A + (size_t)rr * K + c8 * 8);
            *(uint4*)(&As[r][c8 * 8]) = a;
        }
    }
    __syncthreads();

    f32x4 acc[NT] = {};
    const int m = wave * 16 + nl;
    #pragma unroll
    for (int k0 = 0; k0 < K; k0 += 32) {
        half8 af = *(const half8*)(&As[m][k0 + quad * 8]);
        #pragma unroll
        for (int t = 0; t < NT; t++) {
            half8 bf = *(const half8*)(WT + (size_t)(t * 16 + nl) * K + k0 + quad * 8);
            acc[t] = __builtin_amdgcn_mfma_f32_16x16x32_f16(af, bf, acc[t], 0, 0, 0);
        }
    }

    #pragma unroll
    for (int r = 0; r < 4; r++) {
        int grow = block_row + wave * 16 + quad * 4 + r;
        if (grow < M) {
            float sc = scale[grow];
            #pragma unroll
            for (int t = 0; t < NT; t++)
                C[(size_t)grow * NN + t * 16 + nl] = (_Float16)(sc * acc[t][r]);
        }
    }
}

// Unpack 8 halfs (uint4) and acc[j] += v * h[j]
__device__ inline void accum8(float* acc, uint4 p, float v) {
    const __half2* q = (const __half2*)&p;
    #pragma unroll
    for (int k = 0; k < 4; k++) {
        float2 f = __half22float2(q[k]);
        acc[2 * k]     += v * f.x;
        acc[2 * k + 1] += v * f.y;
    }
}

// Layer-1 aggregation: one wave per node. h' already dinv-scaled.
// out = relu(dinv[i]*sum(ew*h'[src]) + b1), fp16.
__global__ void agg1_kernel(const __half* __restrict__ h, const int* __restrict__ row_ptr,
                            const uint2* __restrict__ edges, const float* __restrict__ dinv,
                            const float* __restrict__ b1, __half* __restrict__ out, int n) {
    int node = blockIdx.x * (blockDim.x >> 6) + (threadIdx.x >> 6);
    int lane = threadIdx.x & 63;
    if (node >= n) return;
    int g = lane >> 4;
    int l = lane & 15;
    int beg = row_ptr[node], end = row_ptr[node + 1];
    float acc[8] = {};
    const __half* hb = h + l * 8;
    for (int e0 = beg; e0 < end; e0 += 8) {
        int eA = e0 + g, eB = e0 + 4 + g;
        int cA = min(eA, end - 1), cB = min(eB, end - 1);
        uint2 mA = edges[cA], mB = edges[cB];
        float vA = (eA < end) ? __uint_as_float(mA.y) : 0.f;
        float vB = (eB < end) ? __uint_as_float(mB.y) : 0.f;
        uint4 pA = *(const uint4*)(hb + (size_t)mA.x * 128);
        uint4 pB = *(const uint4*)(hb + (size_t)mB.x * 128);
        accum8(acc, pA, vA);
        accum8(acc, pB, vB);
    }
    #pragma unroll
    for (int j = 0; j < 8; j++) {
        acc[j] += __shfl_xor(acc[j], 32);
        acc[j] += __shfl_xor(acc[j], 16);
    }
    if (g == 0) {
        float di = dinv[node];
        float4 b0 = *(const float4*)(b1 + l * 8);
        float4 b1v = *(const float4*)(b1 + l * 8 + 4);
        float r[8] = {di * acc[0] + b0.x, di * acc[1] + b0.y, di * acc[2] + b0.z,
                      di * acc[3] + b0.w, di * acc[4] + b1v.x, di * acc[5] + b1v.y,
                      di * acc[6] + b1v.z, di * acc[7] + b1v.w};
        #pragma unroll
        for (int j = 0; j < 8; j++) r[j] = r[j] > 0.f ? r[j] : 0.f;
        __half2 o[4];
        #pragma unroll
        for (int k = 0; k < 4; k++) o[k] = __floats2half2_rn(r[2 * k], r[2 * k + 1]);
        *(uint4*)(out + (size_t)node * 128 + l * 8) = *(uint4*)o;
    }
}

// Layer-2 aggregation + log_softmax. h2' already dinv-scaled.
__global__ void agg2_kernel(const __half* __restrict__ h2, const int* __restrict__ row_ptr,
                            const uint2* __restrict__ edges, const float* __restrict__ dinv,
                            const float* __restrict__ b2, float* __restrict__ out, int n) {
    int node = blockIdx.x * (blockDim.x >> 6) + (threadIdx.x >> 6);
    int lane = threadIdx.x & 63;
    if (node >= n) return;
    int g = lane >> 3;
    int l = lane & 7;
    int beg = row_ptr[node], end = row_ptr[node + 1];
    float acc[8] = {};
    const __half* hb = h2 + l * 8;
    for (int e0 = beg; e0 < end; e0 += 16) {
        int eA = e0 + g, eB = e0 + 8 + g;
        int cA = min(eA, end - 1), cB = min(eB, end - 1);
        uint2 mA = edges[cA], mB = edges[cB];
        float vA = (eA < end) ? __uint_as_float(mA.y) : 0.f;
        float vB = (eB < end) ? __uint_as_float(mB.y) : 0.f;
        uint4 pA = *(const uint4*)(hb + (size_t)mA.x * 64);
        uint4 pB = *(const uint4*)(hb + (size_t)mB.x * 64);
        accum8(acc, pA, vA);
        accum8(acc, pB, vB);
    }
    #pragma unroll
    for (int j = 0; j < 8; j++) {
        acc[j] += __shfl_xor(acc[j], 32);
        acc[j] += __shfl_xor(acc[j], 16);
        acc[j] += __shfl_xor(acc[j], 8);
    }
    float di = dinv[node];
    float4 b0 = *(const float4*)(b2 + l * 8);
    float4 b1v = *(const float4*)(b2 + l * 8 + 4);
    acc[0] = di * acc[0] + b0.x;  acc[1] = di * acc[1] + b0.y;
    acc[2] = di * acc[2] + b0.z;  acc[3] = di * acc[3] + b0.w;
    acc[4] = di * acc[4] + b1v.x; acc[5] = di * acc[5] + b1v.y;
    acc[6] = di * acc[6] + b1v.z; acc[7] = di * acc[7] + b1v.w;
    float m = acc[0];
    #pragma unroll
    for (int j = 1; j < 8; j++) m = fmaxf(m, acc[j]);
    #pragma unroll
    for (int off = 1; off < 8; off <<= 1) m = fmaxf(m, __shfl_xor(m, off));
    float s = 0.f;
    #pragma unroll
    for (int j = 0; j < 8; j++) s += expf(acc[j] - m);
    #pragma unroll
    for (int off = 1; off < 8; off <<= 1) s += __shfl_xor(s, off);
    float ls = m + logf(s);
    if (g == 0) {
        float* op = out + (size_t)node * 64 + l * 8;
        *(float4*)(op)     = make_float4(acc[0] - ls, acc[1] - ls, acc[2] - ls, acc[3] - ls);
        *(float4*)(op + 4) = make_float4(acc[4] - ls, acc[5] - ls, acc[6] - ls, acc[7] - ls);
    }
}

extern "C" void kernel_launch(void* const* d_in, const int* in_sizes, int n_in,
                              void* d_out, int out_size, void* d_ws, size_t ws_size,
                              hipStream_t stream) {
    const float* x  = (const float*)d_in[0];
    const int*   ei = (const int*)d_in[1];
    const float* ew = (const float*)d_in[2];
    const float* W1 = (const float*)d_in[3];
    const float* b1 = (const float*)d_in[4];
    const float* W2 = (const float*)d_in[5];
    const float* b2 = (const float*)d_in[6];
    float* out = (float*)d_out;

    const int N = in_sizes[0] / 256;
    const int E = in_sizes[1] / 2;
    const int Et = E + N;
    const int* src = ei;
    const int* dst = ei + E;

    char* w = (char*)d_ws;
    size_t off = 0;
    auto carve = [&](size_t bytes) {
        void* p = w + off;
        off = (off + bytes + 255) & ~(size_t)255;
        return p;
    };
    const int NB = (N + SCAN_CHUNK - 1) / SCAN_CHUNK;
    unsigned long long* degcnt = (unsigned long long*)carve((size_t)N * 8);
    float*    dinv    = (float*)carve((size_t)N * 4);
    int*      counts  = (int*)  carve((size_t)N * 4);
    int*      row_ptr = (int*)  carve((size_t)(N + 1) * 4);
    int*      cursor  = (int*)  carve((size_t)N * 4);
    int*      bsums   = (int*)  carve((size_t)NB * 4);
    uint2*    edges   = (uint2*)carve((size_t)Et * 8);
    _Float16* w1t     = (_Float16*)carve((size_t)256 * 128 * 2);
    _Float16* w2t     = (_Float16*)carve((size_t)128 * 64 * 2);
    _Float16* bufA    = (_Float16*)carve((size_t)N * 128 * 2);  // h'; later h2' (aliased)
    _Float16* bufB    = (_Float16*)carve((size_t)N * 128 * 2);  // h1
    _Float16* bufC    = bufA;

    const int gN = (N + BLK - 1) / BLK;
    const int gE = (E + BLK - 1) / BLK;

    // 1. CSR build
    hipMemsetAsync(degcnt, 0, (size_t)N * 8, stream);
    hist_kernel<<<gE, BLK, 0, stream>>>(dst, ew, degcnt, E);
    dinv_kernel<<<gN, BLK, 0, stream>>>(degcnt, counts, dinv, N);
    scan_partial_kernel<<<NB, 256, 0, stream>>>(counts, bsums, N);
    scan_blocksums_kernel<<<1, 64, 0, stream>>>(bsums, row_ptr, NB, N);
    scan_final_kernel<<<NB, 256, 0, stream>>>(counts, bsums, row_ptr, cursor, edges, N);
    fill_edges_kernel<<<gE, BLK, 0, stream>>>(src, dst, ew, cursor, edges, E);

    // weight transposes (tiny)
    convert_wT_kernel<<<(256 * 128 + 255) / 256, 256, 0, stream>>>(W1, w1t, 256, 128);
    convert_wT_kernel<<<(128 * 64 + 255) / 256, 256, 0, stream>>>(W2, w2t, 128, 64);

    // 2. Layer 1: h' = dinv * (x @ W1), h1 = relu(dinv*agg(h')+b1)
    gemm_mfma_kernel<256, 8, float><<<(N + 63) / 64, 256, 0, stream>>>(x, w1t, dinv, bufA, N);
    agg1_kernel<<<(N + 3) / 4, 256, 0, stream>>>((const __half*)bufA, row_ptr, edges, dinv, b1,
                                                 (__half*)bufB, N);

    // 3. Layer 2: h2' = dinv * (h1 @ W2), out = log_softmax(dinv*agg(h2')+b2)
    gemm_mfma_kernel<128, 4, _Float16><<<(N + 63) / 64, 256, 0, stream>>>(bufB, w2t, dinv, bufC, N);
    agg2_kernel<<<(N + 3) / 4, 256, 0, stream>>>((const __half*)bufC, row_ptr, edges, dinv, b2,
                                                 out, N);
}

// Round 7
// 514.923 us; speedup vs baseline: 2.0921x; 1.1115x over previous
//
#include <hip/hip_runtime.h>
#include <hip/hip_fp16.h>

// GCN 2-layer forward. R1: multi-block scan. R2: fp16 intermediates.
// R3: wide-gather aggregation. R4: packed hist atomic + fp16 MFMA GEMMs.
// R5: normalization reformulated, packed 8B edge records, self-loops in scan.
// R6: bucket-sort CSR build — per-edge global returning atomics (measured
//     ~13G/s rate limit, 121us) replaced by 2-level MSD bucket sort:
//     782 buckets of 128 nodes; LDS ranks; <=100k returning atomics total.
//     Also absorbs hist + dinv + all scan kernels into the bucket pipeline.

#define BLK 256
#define NPB 128          // nodes per bucket (dstlocal = dst & 127, 7 bits)
#define MAXBUCK 1024
#define FCAP 3072        // bucket_final LDS edge capacity (avg ~2050, +20 sigma)

typedef _Float16 half8 __attribute__((ext_vector_type(8)));
typedef float f32x4 __attribute__((ext_vector_type(4)));

// --- 1. bucket histogram (fire-and-forget atomics, LDS-privatized) ---
__global__ __launch_bounds__(256) void bucket_hist_kernel(const int* __restrict__ dst, int E,
                                                          int nbuck, int* __restrict__ bhist) {
    __shared__ int lh[MAXBUCK];
    for (int i = threadIdx.x; i < nbuck; i += 256) lh[i] = 0;
    __syncthreads();
    for (int e = blockIdx.x * 256 + threadIdx.x; e < E; e += gridDim.x * 256)
        atomicAdd(&lh[dst[e] >> 7], 1);
    __syncthreads();
    for (int i = threadIdx.x; i < nbuck; i += 256)
        if (lh[i]) atomicAdd(&bhist[i], lh[i]);
}

// --- 2. dual exclusive scan over buckets: ebBase (intermediate, edges only)
//        and outBase (final, edges + self-loop slots). Also row_ptr[N]. ---
__global__ __launch_bounds__(256) void bucket_scan_kernel(const int* __restrict__ bhist,
                                                          int nbuck, int N,
                                                          int* __restrict__ ebBase,
                                                          int* __restrict__ bcursor,
                                                          int* __restrict__ outBase,
                                                          int* __restrict__ row_ptr) {
    __shared__ int sA[256], sB[256];
    int tid = threadIdx.x;
    int v1[4], v2[4];
    int s1 = 0, s2 = 0;
    #pragma unroll
    for (int j = 0; j < 4; j++) {
        int idx = tid * 4 + j;
        int h = (idx < nbuck) ? bhist[idx] : 0;
        int nodes = 0;
        if (idx < nbuck) {
            nodes = N - idx * NPB;
            nodes = nodes > NPB ? NPB : nodes;
            if (nodes < 0) nodes = 0;
        }
        v1[j] = h; v2[j] = h + nodes;
        s1 += v1[j]; s2 += v2[j];
    }
    sA[tid] = s1; sB[tid] = s2;
    __syncthreads();
    for (int off = 1; off < 256; off <<= 1) {
        int a = (tid >= off) ? sA[tid - off] : 0;
        int b = (tid >= off) ? sB[tid - off] : 0;
        __syncthreads();
        sA[tid] += a; sB[tid] += b;
        __syncthreads();
    }
    int run1 = sA[tid] - s1, run2 = sB[tid] - s2;
    #pragma unroll
    for (int j = 0; j < 4; j++) {
        int idx = tid * 4 + j;
        if (idx < nbuck) {
            ebBase[idx] = run1; bcursor[idx] = run1; outBase[idx] = run2;
        }
        run1 += v1[j]; run2 += v2[j];
    }
    if (tid == 255) { ebBase[nbuck] = run1; row_ptr[N] = run2; }
}

// --- 3. scatter edges into bucket-grouped edgesB. Block reserves space per
//        bucket (<=782 returning atomics/block), local ranks via LDS. ---
__global__ __launch_bounds__(256) void bucket_scatter_kernel(const int* __restrict__ src,
                                                             const int* __restrict__ dst,
                                                             const float* __restrict__ ew,
                                                             int* __restrict__ bcursor,
                                                             uint2* __restrict__ edgesB,
                                                             int E, int nbuck) {
    __shared__ int lh[MAXBUCK];
    __shared__ int lbase[MAXBUCK];
    for (int i = threadIdx.x; i < nbuck; i += 256) lh[i] = 0;
    __syncthreads();
    int chunk = (E + gridDim.x - 1) / gridDim.x;
    int beg = blockIdx.x * chunk;
    int end = min(E, beg + chunk);
    for (int e = beg + threadIdx.x; e < end; e += 256)
        atomicAdd(&lh[dst[e] >> 7], 1);
    __syncthreads();
    for (int i = threadIdx.x; i < nbuck; i += 256) {
        int c = lh[i];
        lbase[i] = c ? atomicAdd(&bcursor[i], c) : 0;
        lh[i] = 0;
    }
    __syncthreads();
    for (int e = beg + threadIdx.x; e < end; e += 256) {
        int d = dst[e];
        int b = d >> 7;
        int r = atomicAdd(&lh[b], 1);   // LDS returning atomic: fast
        edgesB[lbase[b] + r] = make_uint2((unsigned)src[e] | ((unsigned)(d & 127) << 17),
                                          __float_as_uint(ew[e]));
    }
}

// --- 4. per-bucket finalize: counts, weighted degree, row_ptr, dinv,
//        self-loops, dst-grouped final edges. All LDS-local. ---
__global__ __launch_bounds__(256) void bucket_final_kernel(const uint2* __restrict__ edgesB,
                                                           const int* __restrict__ ebBase,
                                                           const int* __restrict__ outBase,
                                                           int* __restrict__ row_ptr,
                                                           float* __restrict__ dinv,
                                                           uint2* __restrict__ edges,
                                                           int N, int nbuck) {
    __shared__ uint2 eb[FCAP];
    __shared__ int cnts[NPB];
    __shared__ float wsum[NPB];
    __shared__ int starts[NPB];
    int b = blockIdx.x;
    int tid = threadIdx.x;
    int beg = ebBase[b];
    int cnt = ebBase[b + 1] - beg;
    if (cnt > FCAP) cnt = FCAP;
    int node0 = b * NPB;
    int nn = N - node0; if (nn > NPB) nn = NPB;
    for (int i = tid; i < nn; i += 256) { cnts[i] = 0; wsum[i] = 0.f; }
    for (int i = tid; i < cnt; i += 256) eb[i] = edgesB[beg + i];
    __syncthreads();
    for (int i = tid; i < cnt; i += 256) {
        int dl = eb[i].x >> 17;
        atomicAdd(&cnts[dl], 1);
        atomicAdd(&wsum[dl], __uint_as_float(eb[i].y));
    }
    __syncthreads();
    if (tid < 64) {                     // wave 0: scan 128 counts (+1 self-loop each)
        int i0 = 2 * tid, i1 = 2 * tid + 1;
        int c0 = (i0 < nn) ? cnts[i0] + 1 : 0;
        int c1 = (i1 < nn) ? cnts[i1] + 1 : 0;
        int s = c0 + c1;
        int incl = s;
        #pragma unroll
        for (int off = 1; off < 64; off <<= 1) {
            int t = __shfl_up(incl, off);
            if (tid >= off) incl += t;
        }
        int excl = incl - s;
        int outB = outBase[b];
        if (i0 < nn) starts[i0] = outB + excl;
        if (i1 < nn) starts[i1] = outB + excl + c0;
    }
    __syncthreads();
    for (int i = tid; i < nn; i += 256) {
        int rp = starts[i];
        int node = node0 + i;
        row_ptr[node] = rp;
        dinv[node] = rsqrtf(wsum[i] + 1.0f);                       // + self-loop weight
        edges[rp] = make_uint2((unsigned)node, __float_as_uint(1.0f));  // self-loop
        cnts[i] = 1;                                               // cursor past self-loop
    }
    __syncthreads();
    for (int i = tid; i < cnt; i += 256) {
        int dl = eb[i].x >> 17;
        int r = atomicAdd(&cnts[dl], 1);
        edges[starts[dl] + r] = make_uint2(eb[i].x & 0x1FFFFu, eb[i].y);
    }
}

// W[K][NN] fp32 -> WT[NN][K] fp16
__global__ void convert_wT_kernel(const float* __restrict__ W, _Float16* __restrict__ WT,
                                  int K, int NN) {
    int i = blockIdx.x * blockDim.x + threadIdx.x;
    if (i < K * NN) {
        int k = i / NN, nn = i % NN;
        WT[(size_t)nn * K + k] = (_Float16)W[i];
    }
}

// MFMA GEMM: C[M,NN] = scale[m] * (A[M,K] @ WT[NN,K]^T), fp16 out.
template<int K, int NT, typename AT>
__global__ __launch_bounds__(256) void gemm_mfma_kernel(const AT* __restrict__ A,
                                                        const _Float16* __restrict__ WT,
                                                        const float* __restrict__ scale,
                                                        _Float16* __restrict__ C, int M) {
    constexpr int NN = NT * 16;
    constexpr int LDA = K + 8;
    __shared__ _Float16 As[64][LDA];
    const int tid = threadIdx.x;
    const int wave = tid >> 6;
    const int lane = tid & 63;
    const int quad = lane >> 4;
    const int nl = lane & 15;
    const int block_row = blockIdx.x * 64;

    if constexpr (sizeof(AT) == 4) {
        #pragma unroll
        for (int i = tid; i < 64 * K / 4; i += 256) {
            int r = i / (K / 4), c4 = i % (K / 4);
            int rr = block_row + r; if (rr > M - 1) rr = M - 1;
            float4 a = *(const float4*)(A + (size_t)rr * K + c4 * 4);
            _Float16 h4[4] = {(_Float16)a.x, (_Float16)a.y, (_Float16)a.z, (_Float16)a.w};
            *(uint2*)(&As[r][c4 * 4]) = *(uint2*)h4;
        }
    } else {
        #pragma unroll
        for (int i = tid; i < 64 * K / 8; i += 256) {
            int r = i / (K / 8), c8 = i % (K / 8);
            int rr = block_row + r; if (rr > M - 1) rr = M - 1;
            uint4 a = *(const uint4*)(A + (size_t)rr * K + c8 * 8);
            *(uint4*)(&As[r][c8 * 8]) = a;
        }
    }
    __syncthreads();

    f32x4 acc[NT] = {};
    const int m = wave * 16 + nl;
    #pragma unroll
    for (int k0 = 0; k0 < K; k0 += 32) {
        half8 af = *(const half8*)(&As[m][k0 + quad * 8]);
        #pragma unroll
        for (int t = 0; t < NT; t++) {
            half8 bf = *(const half8*)(WT + (size_t)(t * 16 + nl) * K + k0 + quad * 8);
            acc[t] = __builtin_amdgcn_mfma_f32_16x16x32_f16(af, bf, acc[t], 0, 0, 0);
        }
    }

    #pragma unroll
    for (int r = 0; r < 4; r++) {
        int grow = block_row + wave * 16 + quad * 4 + r;
        if (grow < M) {
            float sc = scale[grow];
            #pragma unroll
            for (int t = 0; t < NT; t++)
                C[(size_t)grow * NN + t * 16 + nl] = (_Float16)(sc * acc[t][r]);
        }
    }
}

__device__ inline void accum8(float* acc, uint4 p, float v) {
    const __half2* q = (const __half2*)&p;
    #pragma unroll
    for (int k = 0; k < 4; k++) {
        float2 f = __half22float2(q[k]);
        acc[2 * k]     += v * f.x;
        acc[2 * k + 1] += v * f.y;
    }
}

// Layer-1 aggregation: out = relu(dinv[i]*sum(ew*h'[src]) + b1), fp16.
__global__ void agg1_kernel(const __half* __restrict__ h, const int* __restrict__ row_ptr,
                            const uint2* __restrict__ edges, const float* __restrict__ dinv,
                            const float* __restrict__ b1, __half* __restrict__ out, int n) {
    int node = blockIdx.x * (blockDim.x >> 6) + (threadIdx.x >> 6);
    int lane = threadIdx.x & 63;
    if (node >= n) return;
    int g = lane >> 4;
    int l = lane & 15;
    int beg = row_ptr[node], end = row_ptr[node + 1];
    float acc[8] = {};
    const __half* hb = h + l * 8;
    for (int e0 = beg; e0 < end; e0 += 8) {
        int eA = e0 + g, eB = e0 + 4 + g;
        int cA = min(eA, end - 1), cB = min(eB, end - 1);
        uint2 mA = edges[cA], mB = edges[cB];
        float vA = (eA < end) ? __uint_as_float(mA.y) : 0.f;
        float vB = (eB < end) ? __uint_as_float(mB.y) : 0.f;
        uint4 pA = *(const uint4*)(hb + (size_t)mA.x * 128);
        uint4 pB = *(const uint4*)(hb + (size_t)mB.x * 128);
        accum8(acc, pA, vA);
        accum8(acc, pB, vB);
    }
    #pragma unroll
    for (int j = 0; j < 8; j++) {
        acc[j] += __shfl_xor(acc[j], 32);
        acc[j] += __shfl_xor(acc[j], 16);
    }
    if (g == 0) {
        float di = dinv[node];
        float4 b0 = *(const float4*)(b1 + l * 8);
        float4 b1v = *(const float4*)(b1 + l * 8 + 4);
        float r[8] = {di * acc[0] + b0.x, di * acc[1] + b0.y, di * acc[2] + b0.z,
                      di * acc[3] + b0.w, di * acc[4] + b1v.x, di * acc[5] + b1v.y,
                      di * acc[6] + b1v.z, di * acc[7] + b1v.w};
        #pragma unroll
        for (int j = 0; j < 8; j++) r[j] = r[j] > 0.f ? r[j] : 0.f;
        __half2 o[4];
        #pragma unroll
        for (int k = 0; k < 4; k++) o[k] = __floats2half2_rn(r[2 * k], r[2 * k + 1]);
        *(uint4*)(out + (size_t)node * 128 + l * 8) = *(uint4*)o;
    }
}

// Layer-2 aggregation + log_softmax.
__global__ void agg2_kernel(const __half* __restrict__ h2, const int* __restrict__ row_ptr,
                            const uint2* __restrict__ edges, const float* __restrict__ dinv,
                            const float* __restrict__ b2, float* __restrict__ out, int n) {
    int node = blockIdx.x * (blockDim.x >> 6) + (threadIdx.x >> 6);
    int lane = threadIdx.x & 63;
    if (node >= n) return;
    int g = lane >> 3;
    int l = lane & 7;
    int beg = row_ptr[node], end = row_ptr[node + 1];
    float acc[8] = {};
    const __half* hb = h2 + l * 8;
    for (int e0 = beg; e0 < end; e0 += 16) {
        int eA = e0 + g, eB = e0 + 8 + g;
        int cA = min(eA, end - 1), cB = min(eB, end - 1);
        uint2 mA = edges[cA], mB = edges[cB];
        float vA = (eA < end) ? __uint_as_float(mA.y) : 0.f;
        float vB = (eB < end) ? __uint_as_float(mB.y) : 0.f;
        uint4 pA = *(const uint4*)(hb + (size_t)mA.x * 64);
        uint4 pB = *(const uint4*)(hb + (size_t)mB.x * 64);
        accum8(acc, pA, vA);
        accum8(acc, pB, vB);
    }
    #pragma unroll
    for (int j = 0; j < 8; j++) {
        acc[j] += __shfl_xor(acc[j], 32);
        acc[j] += __shfl_xor(acc[j], 16);
        acc[j] += __shfl_xor(acc[j], 8);
    }
    float di = dinv[node];
    float4 b0 = *(const float4*)(b2 + l * 8);
    float4 b1v = *(const float4*)(b2 + l * 8 + 4);
    acc[0] = di * acc[0] + b0.x;  acc[1] = di * acc[1] + b0.y;
    acc[2] = di * acc[2] + b0.z;  acc[3] = di * acc[3] + b0.w;
    acc[4] = di * acc[4] + b1v.x; acc[5] = di * acc[5] + b1v.y;
    acc[6] = di * acc[6] + b1v.z; acc[7] = di * acc[7] + b1v.w;
    float m = acc[0];
    #pragma unroll
    for (int j = 1; j < 8; j++) m = fmaxf(m, acc[j]);
    #pragma unroll
    for (int off = 1; off < 8; off <<= 1) m = fmaxf(m, __shfl_xor(m, off));
    float s = 0.f;
    #pragma unroll
    for (int j = 0; j < 8; j++) s += expf(acc[j] - m);
    #pragma unroll
    for (int off = 1; off < 8; off <<= 1) s += __shfl_xor(s, off);
    float ls = m + logf(s);
    if (g == 0) {
        float* op = out + (size_t)node * 64 + l * 8;
        *(float4*)(op)     = make_float4(acc[0] - ls, acc[1] - ls, acc[2] - ls, acc[3] - ls);
        *(float4*)(op + 4) = make_float4(acc[4] - ls, acc[5] - ls, acc[6] - ls, acc[7] - ls);
    }
}

extern "C" void kernel_launch(void* const* d_in, const int* in_sizes, int n_in,
                              void* d_out, int out_size, void* d_ws, size_t ws_size,
                              hipStream_t stream) {
    const float* x  = (const float*)d_in[0];
    const int*   ei = (const int*)d_in[1];
    const float* ew = (const float*)d_in[2];
    const float* W1 = (const float*)d_in[3];
    const float* b1 = (const float*)d_in[4];
    const float* W2 = (const float*)d_in[5];
    const float* b2 = (const float*)d_in[6];
    float* out = (float*)d_out;

    const int N = in_sizes[0] / 256;
    const int E = in_sizes[1] / 2;
    const int Et = E + N;
    const int* src = ei;
    const int* dst = ei + E;
    const int nbuck = (N + NPB - 1) / NPB;   // 782

    char* w = (char*)d_ws;
    size_t off = 0;
    auto carve = [&](size_t bytes) {
        void* p = w + off;
        off = (off + bytes + 255) & ~(size_t)255;
        return p;
    };
    int*      bhist   = (int*)  carve((size_t)MAXBUCK * 4);
    int*      ebBase  = (int*)  carve((size_t)(MAXBUCK + 1) * 4);
    int*      bcursor = (int*)  carve((size_t)MAXBUCK * 4);
    int*      outBase = (int*)  carve((size_t)MAXBUCK * 4);
    int*      row_ptr = (int*)  carve((size_t)(N + 1) * 4);
    float*    dinv    = (float*)carve((size_t)N * 4);
    uint2*    edgesB  = (uint2*)carve((size_t)E * 8);
    uint2*    edges   = (uint2*)carve((size_t)Et * 8);
    _Float16* w1t     = (_Float16*)carve((size_t)256 * 128 * 2);
    _Float16* w2t     = (_Float16*)carve((size_t)128 * 64 * 2);
    _Float16* bufA    = (_Float16*)carve((size_t)N * 128 * 2);  // h'; later h2' (aliased)
    _Float16* bufB    = (_Float16*)carve((size_t)N * 128 * 2);  // h1
    _Float16* bufC    = bufA;

    // 1. bucket-sort CSR build
    hipMemsetAsync(bhist, 0, (size_t)nbuck * 4, stream);
    bucket_hist_kernel<<<64, 256, 0, stream>>>(dst, E, nbuck, bhist);
    bucket_scan_kernel<<<1, 256, 0, stream>>>(bhist, nbuck, N, ebBase, bcursor, outBase, row_ptr);
    bucket_scatter_kernel<<<128, 256, 0, stream>>>(src, dst, ew, bcursor, edgesB, E, nbuck);
    bucket_final_kernel<<<nbuck, 256, 0, stream>>>(edgesB, ebBase, outBase, row_ptr, dinv,
                                                   edges, N, nbuck);

    // weight transposes (tiny)
    convert_wT_kernel<<<(256 * 128 + 255) / 256, 256, 0, stream>>>(W1, w1t, 256, 128);
    convert_wT_kernel<<<(128 * 64 + 255) / 256, 256, 0, stream>>>(W2, w2t, 128, 64);

    // 2. Layer 1: h' = dinv * (x @ W1), h1 = relu(dinv*agg(h')+b1)
    gemm_mfma_kernel<256, 8, float><<<(N + 63) / 64, 256, 0, stream>>>(x, w1t, dinv, bufA, N);
    agg1_kernel<<<(N + 3) / 4, 256, 0, stream>>>((const __half*)bufA, row_ptr, edges, dinv, b1,
                                                 (__half*)bufB, N);

    // 3. Layer 2: h2' = dinv * (h1 @ W2), out = log_softmax(dinv*agg(h2')+b2)
    gemm_mfma_kernel<128, 4, _Float16><<<(N + 63) / 64, 256, 0, stream>>>(bufB, w2t, dinv, bufC, N);
    agg2_kernel<<<(N + 3) / 4, 256, 0, stream>>>((const __half*)bufC, row_ptr, edges, dinv, b2,
                                                 out, N);
}

// Round 8
// 485.351 us; speedup vs baseline: 2.2196x; 1.0609x over previous
//
#include <hip/hip_runtime.h>
#include <hip/hip_fp16.h>

// GCN 2-layer forward. R1: multi-block scan. R2: fp16 intermediates.
// R3: wide-gather aggregation. R4: packed hist atomic + fp16 MFMA GEMMs.
// R5: reformulated normalization, packed 8B edges, self-loops in scan.
// R6: bucket-sort CSR build (no per-edge global returning atomics).
// R7: LDS-free GEMM — B pre-shuffled to fragment order (1KB contiguous
//     wave loads), A fragments straight from global (cvt in regs), 32
//     rows/wave, fully unrolled K loop. R6's gemm was latency-serialized
//     (MfmaUtil 2.4%, VGPR 52: compiler kept nothing in flight).

#define BLK 256
#define NPB 128          // nodes per bucket (dstlocal = dst & 127)
#define MAXBUCK 1024
#define FCAP 3072        // bucket_final LDS edge capacity

typedef _Float16 half8 __attribute__((ext_vector_type(8)));
typedef float f32x4 __attribute__((ext_vector_type(4)));

// --- 1. bucket histogram (fire-and-forget atomics, LDS-privatized) ---
__global__ __launch_bounds__(256) void bucket_hist_kernel(const int* __restrict__ dst, int E,
                                                          int nbuck, int* __restrict__ bhist) {
    __shared__ int lh[MAXBUCK];
    for (int i = threadIdx.x; i < nbuck; i += 256) lh[i] = 0;
    __syncthreads();
    for (int e = blockIdx.x * 256 + threadIdx.x; e < E; e += gridDim.x * 256)
        atomicAdd(&lh[dst[e] >> 7], 1);
    __syncthreads();
    for (int i = threadIdx.x; i < nbuck; i += 256)
        if (lh[i]) atomicAdd(&bhist[i], lh[i]);
}

// --- 2. dual exclusive scan over buckets ---
__global__ __launch_bounds__(256) void bucket_scan_kernel(const int* __restrict__ bhist,
                                                          int nbuck, int N,
                                                          int* __restrict__ ebBase,
                                                          int* __restrict__ bcursor,
                                                          int* __restrict__ outBase,
                                                          int* __restrict__ row_ptr) {
    __shared__ int sA[256], sB[256];
    int tid = threadIdx.x;
    int v1[4], v2[4];
    int s1 = 0, s2 = 0;
    #pragma unroll
    for (int j = 0; j < 4; j++) {
        int idx = tid * 4 + j;
        int h = (idx < nbuck) ? bhist[idx] : 0;
        int nodes = 0;
        if (idx < nbuck) {
            nodes = N - idx * NPB;
            nodes = nodes > NPB ? NPB : nodes;
            if (nodes < 0) nodes = 0;
        }
        v1[j] = h; v2[j] = h + nodes;
        s1 += v1[j]; s2 += v2[j];
    }
    sA[tid] = s1; sB[tid] = s2;
    __syncthreads();
    for (int off = 1; off < 256; off <<= 1) {
        int a = (tid >= off) ? sA[tid - off] : 0;
        int b = (tid >= off) ? sB[tid - off] : 0;
        __syncthreads();
        sA[tid] += a; sB[tid] += b;
        __syncthreads();
    }
    int run1 = sA[tid] - s1, run2 = sB[tid] - s2;
    #pragma unroll
    for (int j = 0; j < 4; j++) {
        int idx = tid * 4 + j;
        if (idx < nbuck) {
            ebBase[idx] = run1; bcursor[idx] = run1; outBase[idx] = run2;
        }
        run1 += v1[j]; run2 += v2[j];
    }
    if (tid == 255) { ebBase[nbuck] = run1; row_ptr[N] = run2; }
}

// --- 3. scatter edges into bucket-grouped edgesB ---
__global__ __launch_bounds__(256) void bucket_scatter_kernel(const int* __restrict__ src,
                                                             const int* __restrict__ dst,
                                                             const float* __restrict__ ew,
                                                             int* __restrict__ bcursor,
                                                             uint2* __restrict__ edgesB,
                                                             int E, int nbuck) {
    __shared__ int lh[MAXBUCK];
    __shared__ int lbase[MAXBUCK];
    for (int i = threadIdx.x; i < nbuck; i += 256) lh[i] = 0;
    __syncthreads();
    int chunk = (E + gridDim.x - 1) / gridDim.x;
    int beg = blockIdx.x * chunk;
    int end = min(E, beg + chunk);
    for (int e = beg + threadIdx.x; e < end; e += 256)
        atomicAdd(&lh[dst[e] >> 7], 1);
    __syncthreads();
    for (int i = threadIdx.x; i < nbuck; i += 256) {
        int c = lh[i];
        lbase[i] = c ? atomicAdd(&bcursor[i], c) : 0;
        lh[i] = 0;
    }
    __syncthreads();
    for (int e = beg + threadIdx.x; e < end; e += 256) {
        int d = dst[e];
        int b = d >> 7;
        int r = atomicAdd(&lh[b], 1);
        edgesB[lbase[b] + r] = make_uint2((unsigned)src[e] | ((unsigned)(d & 127) << 17),
                                          __float_as_uint(ew[e]));
    }
}

// --- 4. per-bucket finalize ---
__global__ __launch_bounds__(256) void bucket_final_kernel(const uint2* __restrict__ edgesB,
                                                           const int* __restrict__ ebBase,
                                                           const int* __restrict__ outBase,
                                                           int* __restrict__ row_ptr,
                                                           float* __restrict__ dinv,
                                                           uint2* __restrict__ edges,
                                                           int N, int nbuck) {
    __shared__ uint2 eb[FCAP];
    __shared__ int cnts[NPB];
    __shared__ float wsum[NPB];
    __shared__ int starts[NPB];
    int b = blockIdx.x;
    int tid = threadIdx.x;
    int beg = ebBase[b];
    int cnt = ebBase[b + 1] - beg;
    if (cnt > FCAP) cnt = FCAP;
    int node0 = b * NPB;
    int nn = N - node0; if (nn > NPB) nn = NPB;
    for (int i = tid; i < nn; i += 256) { cnts[i] = 0; wsum[i] = 0.f; }
    for (int i = tid; i < cnt; i += 256) eb[i] = edgesB[beg + i];
    __syncthreads();
    for (int i = tid; i < cnt; i += 256) {
        int dl = eb[i].x >> 17;
        atomicAdd(&cnts[dl], 1);
        atomicAdd(&wsum[dl], __uint_as_float(eb[i].y));
    }
    __syncthreads();
    if (tid < 64) {
        int i0 = 2 * tid, i1 = 2 * tid + 1;
        int c0 = (i0 < nn) ? cnts[i0] + 1 : 0;
        int c1 = (i1 < nn) ? cnts[i1] + 1 : 0;
        int s = c0 + c1;
        int incl = s;
        #pragma unroll
        for (int off = 1; off < 64; off <<= 1) {
            int t = __shfl_up(incl, off);
            if (tid >= off) incl += t;
        }
        int excl = incl - s;
        int outB = outBase[b];
        if (i0 < nn) starts[i0] = outB + excl;
        if (i1 < nn) starts[i1] = outB + excl + c0;
    }
    __syncthreads();
    for (int i = tid; i < nn; i += 256) {
        int rp = starts[i];
        int node = node0 + i;
        row_ptr[node] = rp;
        dinv[node] = rsqrtf(wsum[i] + 1.0f);
        edges[rp] = make_uint2((unsigned)node, __float_as_uint(1.0f));
        cnts[i] = 1;
    }
    __syncthreads();
    for (int i = tid; i < cnt; i += 256) {
        int dl = eb[i].x >> 17;
        int r = atomicAdd(&cnts[dl], 1);
        edges[starts[dl] + r] = make_uint2(eb[i].x & 0x1FFFFu, eb[i].y);
    }
}

// W[K][NN] fp32 -> Bord fragment order: Bord[((t*KS+ks)*64+lane)*8+j]
//   = W[ks*32+(lane>>4)*8+j][t*16+(lane&15)]
template<int K, int NT>
__global__ void convert_bord_kernel(const float* __restrict__ W, _Float16* __restrict__ Bord) {
    constexpr int NN = NT * 16;
    constexpr int KS = K / 32;
    int i = blockIdx.x * blockDim.x + threadIdx.x;
    if (i < NT * KS * 64 * 8) {
        int j = i & 7;
        int lane = (i >> 3) & 63;
        int ks = (i >> 9) % KS;
        int t = i / (KS * 512);
        int kk = ks * 32 + (lane >> 4) * 8 + j;
        int nnj = t * 16 + (lane & 15);
        Bord[i] = (_Float16)W[(size_t)kk * NN + nnj];
    }
}

// LDS-free MFMA GEMM: C[M,NN] = scale[m]*(A[M,K] @ B), B in fragment order.
// One wave owns 32 rows (2 row-tiles sharing bf). No barriers.
template<int K, int NT, typename AT>
__global__ __launch_bounds__(256, 2) void gemm_mfma_kernel(const AT* __restrict__ A,
                                                           const _Float16* __restrict__ Bord,
                                                           const float* __restrict__ scale,
                                                           _Float16* __restrict__ C, int M) {
    constexpr int NN = NT * 16;
    constexpr int KS = K / 32;
    const int wave_id = (blockIdx.x * blockDim.x + threadIdx.x) >> 6;
    const int lane = threadIdx.x & 63;
    const int quad = lane >> 4;
    const int nl = lane & 15;
    const int row_base = wave_id * 32;
    if (row_base >= M) return;
    const int m0 = min(row_base + nl, M - 1);
    const int m1 = min(row_base + 16 + nl, M - 1);

    f32x4 acc[2][NT] = {};
    #pragma unroll
    for (int ks = 0; ks < KS; ks++) {
        const int kcol = ks * 32 + quad * 8;
        half8 af0, af1;
        if constexpr (sizeof(AT) == 4) {
            const float* a0 = A + (size_t)m0 * K + kcol;
            const float* a1 = A + (size_t)m1 * K + kcol;
            float4 x0 = *(const float4*)a0, x1 = *(const float4*)(a0 + 4);
            float4 y0 = *(const float4*)a1, y1 = *(const float4*)(a1 + 4);
            af0[0] = (_Float16)x0.x; af0[1] = (_Float16)x0.y;
            af0[2] = (_Float16)x0.z; af0[3] = (_Float16)x0.w;
            af0[4] = (_Float16)x1.x; af0[5] = (_Float16)x1.y;
            af0[6] = (_Float16)x1.z; af0[7] = (_Float16)x1.w;
            af1[0] = (_Float16)y0.x; af1[1] = (_Float16)y0.y;
            af1[2] = (_Float16)y0.z; af1[3] = (_Float16)y0.w;
            af1[4] = (_Float16)y1.x; af1[5] = (_Float16)y1.y;
            af1[6] = (_Float16)y1.z; af1[7] = (_Float16)y1.w;
        } else {
            af0 = *(const half8*)(A + (size_t)m0 * K + kcol);
            af1 = *(const half8*)(A + (size_t)m1 * K + kcol);
        }
        #pragma unroll
        for (int t = 0; t < NT; t++) {
            half8 bf = *(const half8*)(Bord + ((size_t)(t * KS + ks) * 64 + lane) * 8);
            acc[0][t] = __builtin_amdgcn_mfma_f32_16x16x32_f16(af0, bf, acc[0][t], 0, 0, 0);
            acc[1][t] = __builtin_amdgcn_mfma_f32_16x16x32_f16(af1, bf, acc[1][t], 0, 0, 0);
        }
    }
    #pragma unroll
    for (int rt = 0; rt < 2; rt++) {
        #pragma unroll
        for (int r = 0; r < 4; r++) {
            int grow = row_base + rt * 16 + quad * 4 + r;
            if (grow < M) {
                float sc = scale[grow];
                #pragma unroll
                for (int t = 0; t < NT; t++)
                    C[(size_t)grow * NN + t * 16 + nl] = (_Float16)(sc * acc[rt][t][r]);
            }
        }
    }
}

__device__ inline void accum8(float* acc, uint4 p, float v) {
    const __half2* q = (const __half2*)&p;
    #pragma unroll
    for (int k = 0; k < 4; k++) {
        float2 f = __half22float2(q[k]);
        acc[2 * k]     += v * f.x;
        acc[2 * k + 1] += v * f.y;
    }
}

// Layer-1 aggregation: out = relu(dinv[i]*sum(ew*h'[src]) + b1), fp16.
__global__ void agg1_kernel(const __half* __restrict__ h, const int* __restrict__ row_ptr,
                            const uint2* __restrict__ edges, const float* __restrict__ dinv,
                            const float* __restrict__ b1, __half* __restrict__ out, int n) {
    int node = blockIdx.x * (blockDim.x >> 6) + (threadIdx.x >> 6);
    int lane = threadIdx.x & 63;
    if (node >= n) return;
    int g = lane >> 4;
    int l = lane & 15;
    int beg = row_ptr[node], end = row_ptr[node + 1];
    float acc[8] = {};
    const __half* hb = h + l * 8;
    for (int e0 = beg; e0 < end; e0 += 8) {
        int eA = e0 + g, eB = e0 + 4 + g;
        int cA = min(eA, end - 1), cB = min(eB, end - 1);
        uint2 mA = edges[cA], mB = edges[cB];
        float vA = (eA < end) ? __uint_as_float(mA.y) : 0.f;
        float vB = (eB < end) ? __uint_as_float(mB.y) : 0.f;
        uint4 pA = *(const uint4*)(hb + (size_t)mA.x * 128);
        uint4 pB = *(const uint4*)(hb + (size_t)mB.x * 128);
        accum8(acc, pA, vA);
        accum8(acc, pB, vB);
    }
    #pragma unroll
    for (int j = 0; j < 8; j++) {
        acc[j] += __shfl_xor(acc[j], 32);
        acc[j] += __shfl_xor(acc[j], 16);
    }
    if (g == 0) {
        float di = dinv[node];
        float4 b0 = *(const float4*)(b1 + l * 8);
        float4 b1v = *(const float4*)(b1 + l * 8 + 4);
        float r[8] = {di * acc[0] + b0.x, di * acc[1] + b0.y, di * acc[2] + b0.z,
                      di * acc[3] + b0.w, di * acc[4] + b1v.x, di * acc[5] + b1v.y,
                      di * acc[6] + b1v.z, di * acc[7] + b1v.w};
        #pragma unroll
        for (int j = 0; j < 8; j++) r[j] = r[j] > 0.f ? r[j] : 0.f;
        __half2 o[4];
        #pragma unroll
        for (int k = 0; k < 4; k++) o[k] = __floats2half2_rn(r[2 * k], r[2 * k + 1]);
        *(uint4*)(out + (size_t)node * 128 + l * 8) = *(uint4*)o;
    }
}

// Layer-2 aggregation + log_softmax.
__global__ void agg2_kernel(const __half* __restrict__ h2, const int* __restrict__ row_ptr,
                            const uint2* __restrict__ edges, const float* __restrict__ dinv,
                            const float* __restrict__ b2, float* __restrict__ out, int n) {
    int node = blockIdx.x * (blockDim.x >> 6) + (threadIdx.x >> 6);
    int lane = threadIdx.x & 63;
    if (node >= n) return;
    int g = lane >> 3;
    int l = lane & 7;
    int beg = row_ptr[node], end = row_ptr[node + 1];
    float acc[8] = {};
    const __half* hb = h2 + l * 8;
    for (int e0 = beg; e0 < end; e0 += 16) {
        int eA = e0 + g, eB = e0 + 8 + g;
        int cA = min(eA, end - 1), cB = min(eB, end - 1);
        uint2 mA = edges[cA], mB = edges[cB];
        float vA = (eA < end) ? __uint_as_float(mA.y) : 0.f;
        float vB = (eB < end) ? __uint_as_float(mB.y) : 0.f;
        uint4 pA = *(const uint4*)(hb + (size_t)mA.x * 64);
        uint4 pB = *(const uint4*)(hb + (size_t)mB.x * 64);
        accum8(acc, pA, vA);
        accum8(acc, pB, vB);
    }
    #pragma unroll
    for (int j = 0; j < 8; j++) {
        acc[j] += __shfl_xor(acc[j], 32);
        acc[j] += __shfl_xor(acc[j], 16);
        acc[j] += __shfl_xor(acc[j], 8);
    }
    float di = dinv[node];
    float4 b0 = *(const float4*)(b2 + l * 8);
    float4 b1v = *(const float4*)(b2 + l * 8 + 4);
    acc[0] = di * acc[0] + b0.x;  acc[1] = di * acc[1] + b0.y;
    acc[2] = di * acc[2] + b0.z;  acc[3] = di * acc[3] + b0.w;
    acc[4] = di * acc[4] + b1v.x; acc[5] = di * acc[5] + b1v.y;
    acc[6] = di * acc[6] + b1v.z; acc[7] = di * acc[7] + b1v.w;
    float m = acc[0];
    #pragma unroll
    for (int j = 1; j < 8; j++) m = fmaxf(m, acc[j]);
    #pragma unroll
    for (int off = 1; off < 8; off <<= 1) m = fmaxf(m, __shfl_xor(m, off));
    float s = 0.f;
    #pragma unroll
    for (int j = 0; j < 8; j++) s += expf(acc[j] - m);
    #pragma unroll
    for (int off = 1; off < 8; off <<= 1) s += __shfl_xor(s, off);
    float ls = m + logf(s);
    if (g == 0) {
        float* op = out + (size_t)node * 64 + l * 8;
        *(float4*)(op)     = make_float4(acc[0] - ls, acc[1] - ls, acc[2] - ls, acc[3] - ls);
        *(float4*)(op + 4) = make_float4(acc[4] - ls, acc[5] - ls, acc[6] - ls, acc[7] - ls);
    }
}

extern "C" void kernel_launch(void* const* d_in, const int* in_sizes, int n_in,
                              void* d_out, int out_size, void* d_ws, size_t ws_size,
                              hipStream_t stream) {
    const float* x  = (const float*)d_in[0];
    const int*   ei = (const int*)d_in[1];
    const float* ew = (const float*)d_in[2];
    const float* W1 = (const float*)d_in[3];
    const float* b1 = (const float*)d_in[4];
    const float* W2 = (const float*)d_in[5];
    const float* b2 = (const float*)d_in[6];
    float* out = (float*)d_out;

    const int N = in_sizes[0] / 256;
    const int E = in_sizes[1] / 2;
    const int Et = E + N;
    const int* src = ei;
    const int* dst = ei + E;
    const int nbuck = (N + NPB - 1) / NPB;

    char* w = (char*)d_ws;
    size_t off = 0;
    auto carve = [&](size_t bytes) {
        void* p = w + off;
        off = (off + bytes + 255) & ~(size_t)255;
        return p;
    };
    int*      bhist   = (int*)  carve((size_t)MAXBUCK * 4);
    int*      ebBase  = (int*)  carve((size_t)(MAXBUCK + 1) * 4);
    int*      bcursor = (int*)  carve((size_t)MAXBUCK * 4);
    int*      outBase = (int*)  carve((size_t)MAXBUCK * 4);
    int*      row_ptr = (int*)  carve((size_t)(N + 1) * 4);
    float*    dinv    = (float*)carve((size_t)N * 4);
    uint2*    edgesB  = (uint2*)carve((size_t)E * 8);
    uint2*    edges   = (uint2*)carve((size_t)Et * 8);
    _Float16* bord1   = (_Float16*)carve((size_t)256 * 128 * 2);
    _Float16* bord2   = (_Float16*)carve((size_t)128 * 64 * 2);
    _Float16* bufA    = (_Float16*)carve((size_t)N * 128 * 2);  // h'; later h2' (aliased)
    _Float16* bufB    = (_Float16*)carve((size_t)N * 128 * 2);  // h1
    _Float16* bufC    = bufA;

    // 1. bucket-sort CSR build
    hipMemsetAsync(bhist, 0, (size_t)nbuck * 4, stream);
    bucket_hist_kernel<<<64, 256, 0, stream>>>(dst, E, nbuck, bhist);
    bucket_scan_kernel<<<1, 256, 0, stream>>>(bhist, nbuck, N, ebBase, bcursor, outBase, row_ptr);
    bucket_scatter_kernel<<<128, 256, 0, stream>>>(src, dst, ew, bcursor, edgesB, E, nbuck);
    bucket_final_kernel<<<nbuck, 256, 0, stream>>>(edgesB, ebBase, outBase, row_ptr, dinv,
                                                   edges, N, nbuck);

    // weight reorders (tiny)
    convert_bord_kernel<256, 8><<<(256 * 128 + 255) / 256, 256, 0, stream>>>(W1, bord1);
    convert_bord_kernel<128, 4><<<(128 * 64 + 255) / 256, 256, 0, stream>>>(W2, bord2);

    // 2. Layer 1: h' = dinv * (x @ W1), h1 = relu(dinv*agg(h')+b1)
    const int waves1 = (N + 31) / 32;
    gemm_mfma_kernel<256, 8, float><<<(waves1 + 3) / 4, 256, 0, stream>>>(x, bord1, dinv, bufA, N);
    agg1_kernel<<<(N + 3) / 4, 256, 0, stream>>>((const __half*)bufA, row_ptr, edges, dinv, b1,
                                                 (__half*)bufB, N);

    // 3. Layer 2: h2' = dinv * (h1 @ W2), out = log_softmax(dinv*agg(h2')+b2)
    gemm_mfma_kernel<128, 4, _Float16><<<(waves1 + 3) / 4, 256, 0, stream>>>(bufB, bord2, dinv,
                                                                             bufC, N);
    agg2_kernel<<<(N + 3) / 4, 256, 0, stream>>>((const __half*)bufC, row_ptr, edges, dinv, b2,
                                                 out, N);
}

// Round 9
// 463.652 us; speedup vs baseline: 2.3235x; 1.0468x over previous
//
#include <hip/hip_runtime.h>
#include <hip/hip_fp16.h>

// GCN 2-layer forward. R1: multi-block scan. R2: fp16 intermediates.
// R3: wide-gather aggregation. R4: packed hist atomic + fp16 MFMA GEMMs.
// R5: reformulated normalization, packed 8B edges, self-loops in scan.
// R6: bucket-sort CSR build. R7: LDS-free fragment-ordered GEMM.
// R8: GEMM latency fix — full K-strip register prefetch (all A loads issued
//     before first MFMA; R7's VGPR=72 showed zero loads in flight) + 16
//     rows/wave for 2x wave count (R7 occupancy was 22%).

#define BLK 256
#define NPB 128          // nodes per bucket (dstlocal = dst & 127)
#define MAXBUCK 1024
#define FCAP 3072        // bucket_final LDS edge capacity

typedef _Float16 half8 __attribute__((ext_vector_type(8)));
typedef float f32x4 __attribute__((ext_vector_type(4)));

// --- 1. bucket histogram (fire-and-forget atomics, LDS-privatized) ---
__global__ __launch_bounds__(256) void bucket_hist_kernel(const int* __restrict__ dst, int E,
                                                          int nbuck, int* __restrict__ bhist) {
    __shared__ int lh[MAXBUCK];
    for (int i = threadIdx.x; i < nbuck; i += 256) lh[i] = 0;
    __syncthreads();
    for (int e = blockIdx.x * 256 + threadIdx.x; e < E; e += gridDim.x * 256)
        atomicAdd(&lh[dst[e] >> 7], 1);
    __syncthreads();
    for (int i = threadIdx.x; i < nbuck; i += 256)
        if (lh[i]) atomicAdd(&bhist[i], lh[i]);
}

// --- 2. dual exclusive scan over buckets ---
__global__ __launch_bounds__(256) void bucket_scan_kernel(const int* __restrict__ bhist,
                                                          int nbuck, int N,
                                                          int* __restrict__ ebBase,
                                                          int* __restrict__ bcursor,
                                                          int* __restrict__ outBase,
                                                          int* __restrict__ row_ptr) {
    __shared__ int sA[256], sB[256];
    int tid = threadIdx.x;
    int v1[4], v2[4];
    int s1 = 0, s2 = 0;
    #pragma unroll
    for (int j = 0; j < 4; j++) {
        int idx = tid * 4 + j;
        int h = (idx < nbuck) ? bhist[idx] : 0;
        int nodes = 0;
        if (idx < nbuck) {
            nodes = N - idx * NPB;
            nodes = nodes > NPB ? NPB : nodes;
            if (nodes < 0) nodes = 0;
        }
        v1[j] = h; v2[j] = h + nodes;
        s1 += v1[j]; s2 += v2[j];
    }
    sA[tid] = s1; sB[tid] = s2;
    __syncthreads();
    for (int off = 1; off < 256; off <<= 1) {
        int a = (tid >= off) ? sA[tid - off] : 0;
        int b = (tid >= off) ? sB[tid - off] : 0;
        __syncthreads();
        sA[tid] += a; sB[tid] += b;
        __syncthreads();
    }
    int run1 = sA[tid] - s1, run2 = sB[tid] - s2;
    #pragma unroll
    for (int j = 0; j < 4; j++) {
        int idx = tid * 4 + j;
        if (idx < nbuck) {
            ebBase[idx] = run1; bcursor[idx] = run1; outBase[idx] = run2;
        }
        run1 += v1[j]; run2 += v2[j];
    }
    if (tid == 255) { ebBase[nbuck] = run1; row_ptr[N] = run2; }
}

// --- 3. scatter edges into bucket-grouped edgesB ---
__global__ __launch_bounds__(256) void bucket_scatter_kernel(const int* __restrict__ src,
                                                             const int* __restrict__ dst,
                                                             const float* __restrict__ ew,
                                                             int* __restrict__ bcursor,
                                                             uint2* __restrict__ edgesB,
                                                             int E, int nbuck) {
    __shared__ int lh[MAXBUCK];
    __shared__ int lbase[MAXBUCK];
    for (int i = threadIdx.x; i < nbuck; i += 256) lh[i] = 0;
    __syncthreads();
    int chunk = (E + gridDim.x - 1) / gridDim.x;
    int beg = blockIdx.x * chunk;
    int end = min(E, beg + chunk);
    for (int e = beg + threadIdx.x; e < end; e += 256)
        atomicAdd(&lh[dst[e] >> 7], 1);
    __syncthreads();
    for (int i = threadIdx.x; i < nbuck; i += 256) {
        int c = lh[i];
        lbase[i] = c ? atomicAdd(&bcursor[i], c) : 0;
        lh[i] = 0;
    }
    __syncthreads();
    for (int e = beg + threadIdx.x; e < end; e += 256) {
        int d = dst[e];
        int b = d >> 7;
        int r = atomicAdd(&lh[b], 1);
        edgesB[lbase[b] + r] = make_uint2((unsigned)src[e] | ((unsigned)(d & 127) << 17),
                                          __float_as_uint(ew[e]));
    }
}

// --- 4. per-bucket finalize ---
__global__ __launch_bounds__(256) void bucket_final_kernel(const uint2* __restrict__ edgesB,
                                                           const int* __restrict__ ebBase,
                                                           const int* __restrict__ outBase,
                                                           int* __restrict__ row_ptr,
                                                           float* __restrict__ dinv,
                                                           uint2* __restrict__ edges,
                                                           int N, int nbuck) {
    __shared__ uint2 eb[FCAP];
    __shared__ int cnts[NPB];
    __shared__ float wsum[NPB];
    __shared__ int starts[NPB];
    int b = blockIdx.x;
    int tid = threadIdx.x;
    int beg = ebBase[b];
    int cnt = ebBase[b + 1] - beg;
    if (cnt > FCAP) cnt = FCAP;
    int node0 = b * NPB;
    int nn = N - node0; if (nn > NPB) nn = NPB;
    for (int i = tid; i < nn; i += 256) { cnts[i] = 0; wsum[i] = 0.f; }
    for (int i = tid; i < cnt; i += 256) eb[i] = edgesB[beg + i];
    __syncthreads();
    for (int i = tid; i < cnt; i += 256) {
        int dl = eb[i].x >> 17;
        atomicAdd(&cnts[dl], 1);
        atomicAdd(&wsum[dl], __uint_as_float(eb[i].y));
    }
    __syncthreads();
    if (tid < 64) {
        int i0 = 2 * tid, i1 = 2 * tid + 1;
        int c0 = (i0 < nn) ? cnts[i0] + 1 : 0;
        int c1 = (i1 < nn) ? cnts[i1] + 1 : 0;
        int s = c0 + c1;
        int incl = s;
        #pragma unroll
        for (int off = 1; off < 64; off <<= 1) {
            int t = __shfl_up(incl, off);
            if (tid >= off) incl += t;
        }
        int excl = incl - s;
        int outB = outBase[b];
        if (i0 < nn) starts[i0] = outB + excl;
        if (i1 < nn) starts[i1] = outB + excl + c0;
    }
    __syncthreads();
    for (int i = tid; i < nn; i += 256) {
        int rp = starts[i];
        int node = node0 + i;
        row_ptr[node] = rp;
        dinv[node] = rsqrtf(wsum[i] + 1.0f);
        edges[rp] = make_uint2((unsigned)node, __float_as_uint(1.0f));
        cnts[i] = 1;
    }
    __syncthreads();
    for (int i = tid; i < cnt; i += 256) {
        int dl = eb[i].x >> 17;
        int r = atomicAdd(&cnts[dl], 1);
        edges[starts[dl] + r] = make_uint2(eb[i].x & 0x1FFFFu, eb[i].y);
    }
}

// W[K][NN] fp32 -> Bord fragment order: Bord[((t*KS+ks)*64+lane)*8+j]
//   = W[ks*32+(lane>>4)*8+j][t*16+(lane&15)]
template<int K, int NT>
__global__ void convert_bord_kernel(const float* __restrict__ W, _Float16* __restrict__ Bord) {
    constexpr int NN = NT * 16;
    constexpr int KS = K / 32;
    int i = blockIdx.x * blockDim.x + threadIdx.x;
    if (i < NT * KS * 64 * 8) {
        int j = i & 7;
        int lane = (i >> 3) & 63;
        int ks = (i >> 9) % KS;
        int t = i / (KS * 512);
        int kk = ks * 32 + (lane >> 4) * 8 + j;
        int nnj = t * 16 + (lane & 15);
        Bord[i] = (_Float16)W[(size_t)kk * NN + nnj];
    }
}

// LDS-free MFMA GEMM, full K-strip register prefetch. One wave owns 16 rows.
// C[M,NN] = scale[m]*(A[M,K] @ B), B pre-shuffled to fragment order.
template<int K, int NT, int MINW, typename AT>
__global__ __launch_bounds__(256, MINW) void gemm_mfma_kernel(const AT* __restrict__ A,
                                                              const _Float16* __restrict__ Bord,
                                                              const float* __restrict__ scale,
                                                              _Float16* __restrict__ C, int M) {
    constexpr int NN = NT * 16;
    constexpr int KS = K / 32;
    const int wave_id = (blockIdx.x * blockDim.x + threadIdx.x) >> 6;
    const int lane = threadIdx.x & 63;
    const int quad = lane >> 4;
    const int nl = lane & 15;
    const int row_base = wave_id * 16;
    if (row_base >= M) return;
    const int m = min(row_base + nl, M - 1);

    // ---- prefetch the whole K-strip: all loads issued before first use ----
    float4 raw[KS][2];   // fp32 source path
    half8 afr[KS];       // fp16 source path
    if constexpr (sizeof(AT) == 4) {
        const float* ap = (const float*)A + (size_t)m * K + quad * 8;
        #pragma unroll
        for (int ks = 0; ks < KS; ks++) {
            raw[ks][0] = *(const float4*)(ap + ks * 32);
            raw[ks][1] = *(const float4*)(ap + ks * 32 + 4);
        }
    } else {
        const _Float16* ap = (const _Float16*)A + (size_t)m * K + quad * 8;
        #pragma unroll
        for (int ks = 0; ks < KS; ks++)
            afr[ks] = *(const half8*)(ap + ks * 32);
    }

    f32x4 acc[NT] = {};
    #pragma unroll
    for (int ks = 0; ks < KS; ks++) {
        half8 af;
        if constexpr (sizeof(AT) == 4) {
            af[0] = (_Float16)raw[ks][0].x; af[1] = (_Float16)raw[ks][0].y;
            af[2] = (_Float16)raw[ks][0].z; af[3] = (_Float16)raw[ks][0].w;
            af[4] = (_Float16)raw[ks][1].x; af[5] = (_Float16)raw[ks][1].y;
            af[6] = (_Float16)raw[ks][1].z; af[7] = (_Float16)raw[ks][1].w;
        } else {
            af = afr[ks];
        }
        #pragma unroll
        for (int t = 0; t < NT; t++) {
            half8 bf = *(const half8*)(Bord + ((size_t)(t * KS + ks) * 64 + lane) * 8);
            acc[t] = __builtin_amdgcn_mfma_f32_16x16x32_f16(af, bf, acc[t], 0, 0, 0);
        }
    }

    #pragma unroll
    for (int r = 0; r < 4; r++) {
        int grow = row_base + quad * 4 + r;
        if (grow < M) {
            float sc = scale[grow];
            #pragma unroll
            for (int t = 0; t < NT; t++)
                C[(size_t)grow * NN + t * 16 + nl] = (_Float16)(sc * acc[t][r]);
        }
    }
}

__device__ inline void accum8(float* acc, uint4 p, float v) {
    const __half2* q = (const __half2*)&p;
    #pragma unroll
    for (int k = 0; k < 4; k++) {
        float2 f = __half22float2(q[k]);
        acc[2 * k]     += v * f.x;
        acc[2 * k + 1] += v * f.y;
    }
}

// Layer-1 aggregation: out = relu(dinv[i]*sum(ew*h'[src]) + b1), fp16.
__global__ void agg1_kernel(const __half* __restrict__ h, const int* __restrict__ row_ptr,
                            const uint2* __restrict__ edges, const float* __restrict__ dinv,
                            const float* __restrict__ b1, __half* __restrict__ out, int n) {
    int node = blockIdx.x * (blockDim.x >> 6) + (threadIdx.x >> 6);
    int lane = threadIdx.x & 63;
    if (node >= n) return;
    int g = lane >> 4;
    int l = lane & 15;
    int beg = row_ptr[node], end = row_ptr[node + 1];
    float acc[8] = {};
    const __half* hb = h + l * 8;
    for (int e0 = beg; e0 < end; e0 += 8) {
        int eA = e0 + g, eB = e0 + 4 + g;
        int cA = min(eA, end - 1), cB = min(eB, end - 1);
        uint2 mA = edges[cA], mB = edges[cB];
        float vA = (eA < end) ? __uint_as_float(mA.y) : 0.f;
        float vB = (eB < end) ? __uint_as_float(mB.y) : 0.f;
        uint4 pA = *(const uint4*)(hb + (size_t)mA.x * 128);
        uint4 pB = *(const uint4*)(hb + (size_t)mB.x * 128);
        accum8(acc, pA, vA);
        accum8(acc, pB, vB);
    }
    #pragma unroll
    for (int j = 0; j < 8; j++) {
        acc[j] += __shfl_xor(acc[j], 32);
        acc[j] += __shfl_xor(acc[j], 16);
    }
    if (g == 0) {
        float di = dinv[node];
        float4 b0 = *(const float4*)(b1 + l * 8);
        float4 b1v = *(const float4*)(b1 + l * 8 + 4);
        float r[8] = {di * acc[0] + b0.x, di * acc[1] + b0.y, di * acc[2] + b0.z,
                      di * acc[3] + b0.w, di * acc[4] + b1v.x, di * acc[5] + b1v.y,
                      di * acc[6] + b1v.z, di * acc[7] + b1v.w};
        #pragma unroll
        for (int j = 0; j < 8; j++) r[j] = r[j] > 0.f ? r[j] : 0.f;
        __half2 o[4];
        #pragma unroll
        for (int k = 0; k < 4; k++) o[k] = __floats2half2_rn(r[2 * k], r[2 * k + 1]);
        *(uint4*)(out + (size_t)node * 128 + l * 8) = *(uint4*)o;
    }
}

// Layer-2 aggregation + log_softmax.
__global__ void agg2_kernel(const __half* __restrict__ h2, const int* __restrict__ row_ptr,
                            const uint2* __restrict__ edges, const float* __restrict__ dinv,
                            const float* __restrict__ b2, float* __restrict__ out, int n) {
    int node = blockIdx.x * (blockDim.x >> 6) + (threadIdx.x >> 6);
    int lane = threadIdx.x & 63;
    if (node >= n) return;
    int g = lane >> 3;
    int l = lane & 7;
    int beg = row_ptr[node], end = row_ptr[node + 1];
    float acc[8] = {};
    const __half* hb = h2 + l * 8;
    for (int e0 = beg; e0 < end; e0 += 16) {
        int eA = e0 + g, eB = e0 + 8 + g;
        int cA = min(eA, end - 1), cB = min(eB, end - 1);
        uint2 mA = edges[cA], mB = edges[cB];
        float vA = (eA < end) ? __uint_as_float(mA.y) : 0.f;
        float vB = (eB < end) ? __uint_as_float(mB.y) : 0.f;
        uint4 pA = *(const uint4*)(hb + (size_t)mA.x * 64);
        uint4 pB = *(const uint4*)(hb + (size_t)mB.x * 64);
        accum8(acc, pA, vA);
        accum8(acc, pB, vB);
    }
    #pragma unroll
    for (int j = 0; j < 8; j++) {
        acc[j] += __shfl_xor(acc[j], 32);
        acc[j] += __shfl_xor(acc[j], 16);
        acc[j] += __shfl_xor(acc[j], 8);
    }
    float di = dinv[node];
    float4 b0 = *(const float4*)(b2 + l * 8);
    float4 b1v = *(const float4*)(b2 + l * 8 + 4);
    acc[0] = di * acc[0] + b0.x;  acc[1] = di * acc[1] + b0.y;
    acc[2] = di * acc[2] + b0.z;  acc[3] = di * acc[3] + b0.w;
    acc[4] = di * acc[4] + b1v.x; acc[5] = di * acc[5] + b1v.y;
    acc[6] = di * acc[6] + b1v.z; acc[7] = di * acc[7] + b1v.w;
    float m = acc[0];
    #pragma unroll
    for (int j = 1; j < 8; j++) m = fmaxf(m, acc[j]);
    #pragma unroll
    for (int off = 1; off < 8; off <<= 1) m = fmaxf(m, __shfl_xor(m, off));
    float s = 0.f;
    #pragma unroll
    for (int j = 0; j < 8; j++) s += expf(acc[j] - m);
    #pragma unroll
    for (int off = 1; off < 8; off <<= 1) s += __shfl_xor(s, off);
    float ls = m + logf(s);
    if (g == 0) {
        float* op = out + (size_t)node * 64 + l * 8;
        *(float4*)(op)     = make_float4(acc[0] - ls, acc[1] - ls, acc[2] - ls, acc[3] - ls);
        *(float4*)(op + 4) = make_float4(acc[4] - ls, acc[5] - ls, acc[6] - ls, acc[7] - ls);
    }
}

extern "C" void kernel_launch(void* const* d_in, const int* in_sizes, int n_in,
                              void* d_out, int out_size, void* d_ws, size_t ws_size,
                              hipStream_t stream) {
    const float* x  = (const float*)d_in[0];
    const int*   ei = (const int*)d_in[1];
    const float* ew = (const float*)d_in[2];
    const float* W1 = (const float*)d_in[3];
    const float* b1 = (const float*)d_in[4];
    const float* W2 = (const float*)d_in[5];
    const float* b2 = (const float*)d_in[6];
    float* out = (float*)d_out;

    const int N = in_sizes[0] / 256;
    const int E = in_sizes[1] / 2;
    const int Et = E + N;
    const int* src = ei;
    const int* dst = ei + E;
    const int nbuck = (N + NPB - 1) / NPB;

    char* w = (char*)d_ws;
    size_t off = 0;
    auto carve = [&](size_t bytes) {
        void* p = w + off;
        off = (off + bytes + 255) & ~(size_t)255;
        return p;
    };
    int*      bhist   = (int*)  carve((size_t)MAXBUCK * 4);
    int*      ebBase  = (int*)  carve((size_t)(MAXBUCK + 1) * 4);
    int*      bcursor = (int*)  carve((size_t)MAXBUCK * 4);
    int*      outBase = (int*)  carve((size_t)MAXBUCK * 4);
    int*      row_ptr = (int*)  carve((size_t)(N + 1) * 4);
    float*    dinv    = (float*)carve((size_t)N * 4);
    uint2*    edgesB  = (uint2*)carve((size_t)E * 8);
    uint2*    edges   = (uint2*)carve((size_t)Et * 8);
    _Float16* bord1   = (_Float16*)carve((size_t)256 * 128 * 2);
    _Float16* bord2   = (_Float16*)carve((size_t)128 * 64 * 2);
    _Float16* bufA    = (_Float16*)carve((size_t)N * 128 * 2);  // h'; later h2' (aliased)
    _Float16* bufB    = (_Float16*)carve((size_t)N * 128 * 2);  // h1
    _Float16* bufC    = bufA;

    // 1. bucket-sort CSR build
    hipMemsetAsync(bhist, 0, (size_t)nbuck * 4, stream);
    bucket_hist_kernel<<<64, 256, 0, stream>>>(dst, E, nbuck, bhist);
    bucket_scan_kernel<<<1, 256, 0, stream>>>(bhist, nbuck, N, ebBase, bcursor, outBase, row_ptr);
    bucket_scatter_kernel<<<128, 256, 0, stream>>>(src, dst, ew, bcursor, edgesB, E, nbuck);
    bucket_final_kernel<<<nbuck, 256, 0, stream>>>(edgesB, ebBase, outBase, row_ptr, dinv,
                                                   edges, N, nbuck);

    // weight reorders (tiny)
    convert_bord_kernel<256, 8><<<(256 * 128 + 255) / 256, 256, 0, stream>>>(W1, bord1);
    convert_bord_kernel<128, 4><<<(128 * 64 + 255) / 256, 256, 0, stream>>>(W2, bord2);

    // 2. Layer 1: h' = dinv * (x @ W1), h1 = relu(dinv*agg(h')+b1)
    const int waves = (N + 15) / 16;            // 16 rows per wave
    const int gemm_blocks = (waves + 3) / 4;    // 4 waves per block
    gemm_mfma_kernel<256, 8, 4, float><<<gemm_blocks, 256, 0, stream>>>(x, bord1, dinv, bufA, N);
    agg1_kernel<<<(N + 3) / 4, 256, 0, stream>>>((const __half*)bufA, row_ptr, edges, dinv, b1,
                                                 (__half*)bufB, N);

    // 3. Layer 2: h2' = dinv * (h1 @ W2), out = log_softmax(dinv*agg(h2')+b2)
    gemm_mfma_kernel<128, 4, 6, _Float16><<<gemm_blocks, 256, 0, stream>>>(bufB, bord2, dinv,
                                                                           bufC, N);
    agg2_kernel<<<(N + 3) / 4, 256, 0, stream>>>((const __half*)bufC, row_ptr, edges, dinv, b2,
                                                 out, N);
}